// Round 1
// baseline (422.252 us; speedup 1.0000x reference)
//
#include <hip/hip_runtime.h>
#include <hip/hip_bf16.h>

using bf16 = __hip_bfloat16;
typedef __attribute__((ext_vector_type(8))) short short8;   // 8 x bf16 (4 VGPRs) MFMA A/B frag
typedef __attribute__((ext_vector_type(4))) float f32x4;    // MFMA C/D frag

#define GAS __attribute__((address_space(1)))
#define LAS __attribute__((address_space(3)))

__device__ __forceinline__ void gld_lds16(const void* g, void* l) {
  __builtin_amdgcn_global_load_lds((const GAS void*)g, (LAS void*)l, 16, 0, 0);
}

__device__ __forceinline__ unsigned short f2bfu(float f) {
  bf16 h = __float2bfloat16(f);
  return *reinterpret_cast<unsigned short*>(&h);
}

// ---------------- weight f32 -> bf16 ----------------
__global__ __launch_bounds__(256) void cvt_f32_bf16(const float* __restrict__ in,
                                                    bf16* __restrict__ out, int n4) {
  int i = blockIdx.x * 256 + threadIdx.x;
  if (i >= n4) return;
  float4 v = reinterpret_cast<const float4*>(in)[i];
  ushort4 o;
  o.x = f2bfu(v.x); o.y = f2bfu(v.y); o.z = f2bfu(v.z); o.w = f2bfu(v.w);
  reinterpret_cast<ushort4*>(out)[i] = o;
}

// ---------------- LayerNorm (fp32 in, bf16 out), one wave per 512-row ----------------
__global__ __launch_bounds__(256) void ln_kernel(const float* __restrict__ x,
                                                 const float* __restrict__ g,
                                                 const float* __restrict__ b,
                                                 bf16* __restrict__ out) {
  const int row = blockIdx.x * 4 + (threadIdx.x >> 6);
  const int lane = threadIdx.x & 63;
  const float4* xr = reinterpret_cast<const float4*>(x + (size_t)row * 512);
  float4 v0 = xr[lane], v1 = xr[64 + lane];
  float s  = v0.x + v0.y + v0.z + v0.w + v1.x + v1.y + v1.z + v1.w;
  float s2 = v0.x*v0.x + v0.y*v0.y + v0.z*v0.z + v0.w*v0.w
           + v1.x*v1.x + v1.y*v1.y + v1.z*v1.z + v1.w*v1.w;
  #pragma unroll
  for (int d = 1; d < 64; d <<= 1) { s += __shfl_xor(s, d); s2 += __shfl_xor(s2, d); }
  const float mu = s * (1.0f / 512.0f);
  const float var = s2 * (1.0f / 512.0f) - mu * mu;
  const float rstd = rsqrtf(var + 1e-5f);
  const float4* g4 = reinterpret_cast<const float4*>(g);
  const float4* b4 = reinterpret_cast<const float4*>(b);
  float4 ga = g4[lane], gb = g4[64 + lane], ba = b4[lane], bb = b4[64 + lane];
  ushort4 o0, o1;
  o0.x = f2bfu((v0.x - mu) * rstd * ga.x + ba.x);
  o0.y = f2bfu((v0.y - mu) * rstd * ga.y + ba.y);
  o0.z = f2bfu((v0.z - mu) * rstd * ga.z + ba.z);
  o0.w = f2bfu((v0.w - mu) * rstd * ga.w + ba.w);
  o1.x = f2bfu((v1.x - mu) * rstd * gb.x + bb.x);
  o1.y = f2bfu((v1.y - mu) * rstd * gb.y + bb.y);
  o1.z = f2bfu((v1.z - mu) * rstd * gb.z + bb.z);
  o1.w = f2bfu((v1.w - mu) * rstd * gb.w + bb.w);
  ushort4* orow = reinterpret_cast<ushort4*>(out + (size_t)row * 512);
  orow[lane] = o0;
  orow[64 + lane] = o1;
}

// ---------------- GEMM: C[M,N] = A[M,K] * B[N,K]^T (+bias, epilogue) ----------------
// EPI 0: store bf16.  EPI 1: GELU(exact) then bf16.  EPI 2: + resid(f32), store f32.
template <int EPI>
__global__ __launch_bounds__(256) void gemm_bt(const bf16* __restrict__ A,
                                               const bf16* __restrict__ B,
                                               const float* __restrict__ bias,
                                               const float* __restrict__ resid,
                                               void* __restrict__ Cv,
                                               int M, int N, int K) {
  __shared__ bf16 As[128 * 32];
  __shared__ bf16 Bs[128 * 32];
  const int tid = threadIdx.x;
  const int lane = tid & 63, wid = tid >> 6;
  const int lr = lane & 15, lg = lane >> 4;
  const int row0 = blockIdx.x * 128, col0 = blockIdx.y * 128;
  const int wr = (wid >> 1) * 64, wc = (wid & 1) * 64;
  f32x4 acc[4][4] = {};
  const int r1 = tid >> 2,          c1 = (tid & 3) * 8;
  const int r2 = (256 + tid) >> 2,  c2 = ((256 + tid) & 3) * 8;
  for (int kt = 0; kt < K; kt += 32) {
    __syncthreads();
    gld_lds16(A + (size_t)(row0 + r1) * K + kt + c1, As + tid * 8);
    gld_lds16(A + (size_t)(row0 + r2) * K + kt + c2, As + (256 + tid) * 8);
    gld_lds16(B + (size_t)(col0 + r1) * K + kt + c1, Bs + tid * 8);
    gld_lds16(B + (size_t)(col0 + r2) * K + kt + c2, Bs + (256 + tid) * 8);
    __syncthreads();
    short8 af[4], bfr[4];
    #pragma unroll
    for (int mi = 0; mi < 4; ++mi)
      af[mi] = *reinterpret_cast<const short8*>(&As[(wr + mi * 16 + lr) * 32 + lg * 8]);
    #pragma unroll
    for (int nj = 0; nj < 4; ++nj)
      bfr[nj] = *reinterpret_cast<const short8*>(&Bs[(wc + nj * 16 + lr) * 32 + lg * 8]);
    #pragma unroll
    for (int mi = 0; mi < 4; ++mi)
      #pragma unroll
      for (int nj = 0; nj < 4; ++nj)
        acc[mi][nj] = __builtin_amdgcn_mfma_f32_16x16x32_bf16(af[mi], bfr[nj], acc[mi][nj], 0, 0, 0);
  }
  #pragma unroll
  for (int mi = 0; mi < 4; ++mi) {
    #pragma unroll
    for (int nj = 0; nj < 4; ++nj) {
      const int col = col0 + wc + nj * 16 + lr;
      const float bv = bias ? bias[col] : 0.0f;
      #pragma unroll
      for (int rg = 0; rg < 4; ++rg) {
        const int row = row0 + wr + mi * 16 + lg * 4 + rg;
        float v = acc[mi][nj][rg] + bv;
        if constexpr (EPI == 1) v = 0.5f * v * (1.0f + erff(v * 0.70710678118654752f));
        if constexpr (EPI == 2) {
          reinterpret_cast<float*>(Cv)[(size_t)row * N + col] = v + resid[(size_t)row * N + col];
        } else {
          reinterpret_cast<bf16*>(Cv)[(size_t)row * N + col] = __float2bfloat16(v);
        }
      }
    }
  }
}

// ---------------- reshape QKV: C[8192,1536] -> q,k [B,H,N,D] (q pre-scaled 1/8), vt [B,H,D,N] ----------------
__global__ __launch_bounds__(256) void reshape_qkv(const bf16* __restrict__ C,
                                                   bf16* __restrict__ q,
                                                   bf16* __restrict__ k,
                                                   bf16* __restrict__ vt) {
  const int nt = blockIdx.x;   // 64-row tile within batch (0..63)
  const int bh = blockIdx.y;   // 0..15
  const int b = bh >> 3, h = bh & 7;
  __shared__ bf16 vs[64][65];
  const int tid = threadIdx.x;
  #pragma unroll
  for (int i = 0; i < 16; ++i) {
    const int idx = i * 256 + tid;
    const int rr = idx >> 6, c = idx & 63;
    const size_t crow = ((size_t)b * 4096 + nt * 64 + rr) * 1536;
    const size_t onb = ((size_t)bh * 4096 + nt * 64 + rr) * 64 + c;
    q[onb] = __float2bfloat16(__bfloat162float(C[crow + h * 64 + c]) * 0.125f);
    k[onb] = C[crow + 512 + h * 64 + c];
    vs[rr][c] = C[crow + 1024 + h * 64 + c];
  }
  __syncthreads();
  #pragma unroll
  for (int i = 0; i < 16; ++i) {
    const int idx = i * 256 + tid;
    const int d = idx >> 6, n = idx & 63;
    vt[((size_t)bh * 64 + d) * 4096 + nt * 64 + n] = vs[n][d];
  }
}

// ---------------- flash attention: Q[BH,N,D] (scaled), K[BH,N,D], Vt[BH,D,N] -> Out[B,N,C] bf16 ----------------
__global__ __launch_bounds__(256) void attn_kernel(const bf16* __restrict__ Q,
                                                   const bf16* __restrict__ K,
                                                   const bf16* __restrict__ Vt,
                                                   bf16* __restrict__ Out) {
  const int qt = blockIdx.x;   // 0..31
  const int bh = blockIdx.y;   // 0..15
  const int b = bh >> 3, h = bh & 7;
  __shared__ bf16 Qs[128 * 64];
  __shared__ bf16 Ks[128 * 64];
  __shared__ bf16 Vs[64 * 128];     // transposed V tile: [d][kv]
  __shared__ bf16 Ps[4][32 * 128];  // per-wave P
  const int tid = threadIdx.x, wid = tid >> 6, lane = tid & 63;
  const int lr = lane & 15, lg = lane >> 4;
  const bf16* Qg = Q + ((size_t)bh * 4096 + qt * 128) * 64;
  const bf16* Kg = K + (size_t)bh * 4096 * 64;
  const bf16* Vg = Vt + (size_t)bh * 64 * 4096;
  #pragma unroll
  for (int i = 0; i < 4; ++i) {
    const int g = i * 256 + tid;
    gld_lds16(Qg + g * 8, Qs + g * 8);
  }
  f32x4 Oa[2][4] = {};
  float mrow[2][4], lrow[2][4];
  #pragma unroll
  for (int mi = 0; mi < 2; ++mi)
    #pragma unroll
    for (int rg = 0; rg < 4; ++rg) { mrow[mi][rg] = -1e30f; lrow[mi][rg] = 0.0f; }

  for (int t = 0; t < 32; ++t) {
    __syncthreads();   // prior tile fully consumed (also drains Q stage on t==0)
    const bf16* Kt = Kg + (size_t)t * 128 * 64;
    #pragma unroll
    for (int i = 0; i < 4; ++i) {
      const int g = i * 256 + tid;
      gld_lds16(Kt + g * 8, Ks + g * 8);
    }
    #pragma unroll
    for (int i = 0; i < 4; ++i) {
      const int g = i * 256 + tid;
      const int rr = g >> 4, c8 = (g & 15) * 8;
      gld_lds16(Vg + (size_t)rr * 4096 + t * 128 + c8, Vs + g * 8);
    }
    __syncthreads();
    // ---- S = Q K^T (this wave's 32 q-rows x 128 kv) ----
    f32x4 Sa[2][8];
    short8 aq[2][2];
    #pragma unroll
    for (int mi = 0; mi < 2; ++mi)
      #pragma unroll
      for (int kk = 0; kk < 2; ++kk)
        aq[mi][kk] = *reinterpret_cast<const short8*>(
            &Qs[(wid * 32 + mi * 16 + lr) * 64 + kk * 32 + lg * 8]);
    #pragma unroll
    for (int nj = 0; nj < 8; ++nj) {
      short8 bk0 = *reinterpret_cast<const short8*>(&Ks[(nj * 16 + lr) * 64 + lg * 8]);
      short8 bk1 = *reinterpret_cast<const short8*>(&Ks[(nj * 16 + lr) * 64 + 32 + lg * 8]);
      #pragma unroll
      for (int mi = 0; mi < 2; ++mi) {
        f32x4 z = {0.0f, 0.0f, 0.0f, 0.0f};
        z = __builtin_amdgcn_mfma_f32_16x16x32_bf16(aq[mi][0], bk0, z, 0, 0, 0);
        Sa[mi][nj] = __builtin_amdgcn_mfma_f32_16x16x32_bf16(aq[mi][1], bk1, z, 0, 0, 0);
      }
    }
    // ---- online softmax (rows live in 16-lane groups) ----
    #pragma unroll
    for (int mi = 0; mi < 2; ++mi) {
      #pragma unroll
      for (int rg = 0; rg < 4; ++rg) {
        float rmax = Sa[mi][0][rg];
        #pragma unroll
        for (int nj = 1; nj < 8; ++nj) rmax = fmaxf(rmax, Sa[mi][nj][rg]);
        #pragma unroll
        for (int s = 1; s < 16; s <<= 1) rmax = fmaxf(rmax, __shfl_xor(rmax, s));
        const float mnew = fmaxf(mrow[mi][rg], rmax);
        const float fsc = __expf(mrow[mi][rg] - mnew);
        float rsum = 0.0f;
        #pragma unroll
        for (int nj = 0; nj < 8; ++nj) {
          float p = __expf(Sa[mi][nj][rg] - mnew);
          Sa[mi][nj][rg] = p;
          rsum += p;
        }
        #pragma unroll
        for (int s = 1; s < 16; s <<= 1) rsum += __shfl_xor(rsum, s);
        lrow[mi][rg] = lrow[mi][rg] * fsc + rsum;
        mrow[mi][rg] = mnew;
        #pragma unroll
        for (int dj = 0; dj < 4; ++dj) Oa[mi][dj][rg] *= fsc;
      }
    }
    // ---- P -> LDS (C-frag layout -> A-frag layout round-trip), wave-private ----
    #pragma unroll
    for (int mi = 0; mi < 2; ++mi)
      #pragma unroll
      for (int nj = 0; nj < 8; ++nj)
        #pragma unroll
        for (int rg = 0; rg < 4; ++rg)
          Ps[wid][(mi * 16 + lg * 4 + rg) * 128 + nj * 16 + lr] =
              __float2bfloat16(Sa[mi][nj][rg]);
    // ---- O += P V ----
    #pragma unroll
    for (int kk = 0; kk < 4; ++kk) {
      short8 bv[4];
      #pragma unroll
      for (int dj = 0; dj < 4; ++dj)
        bv[dj] = *reinterpret_cast<const short8*>(&Vs[(dj * 16 + lr) * 128 + kk * 32 + lg * 8]);
      #pragma unroll
      for (int mi = 0; mi < 2; ++mi) {
        short8 ap = *reinterpret_cast<const short8*>(&Ps[wid][(mi * 16 + lr) * 128 + kk * 32 + lg * 8]);
        #pragma unroll
        for (int dj = 0; dj < 4; ++dj)
          Oa[mi][dj] = __builtin_amdgcn_mfma_f32_16x16x32_bf16(ap, bv[dj], Oa[mi][dj], 0, 0, 0);
      }
    }
  }
  // ---- normalize + store to [B,N,C] ----
  #pragma unroll
  for (int mi = 0; mi < 2; ++mi) {
    #pragma unroll
    for (int dj = 0; dj < 4; ++dj) {
      #pragma unroll
      for (int rg = 0; rg < 4; ++rg) {
        const int n = qt * 128 + wid * 32 + mi * 16 + lg * 4 + rg;
        const int d = dj * 16 + lr;
        const float v = Oa[mi][dj][rg] / lrow[mi][rg];
        Out[((size_t)b * 4096 + n) * 512 + h * 64 + d] = __float2bfloat16(v);
      }
    }
  }
}

// ---------------- host ----------------
extern "C" void kernel_launch(void* const* d_in, const int* in_sizes, int n_in,
                              void* d_out, int out_size, void* d_ws, size_t ws_size,
                              hipStream_t stream) {
  const float* x      = (const float*)d_in[0];
  const float* ln1_g  = (const float*)d_in[1];
  const float* ln1_b  = (const float*)d_in[2];
  const float* ln2_g  = (const float*)d_in[3];
  const float* ln2_b  = (const float*)d_in[4];
  const float* qkv_w  = (const float*)d_in[5];
  const float* qkv_b  = (const float*)d_in[6];
  const float* proj_w = (const float*)d_in[7];
  const float* proj_b = (const float*)d_in[8];
  const float* fc1_w  = (const float*)d_in[9];
  const float* fc1_b  = (const float*)d_in[10];
  const float* fc2_w  = (const float*)d_in[11];
  const float* fc2_b  = (const float*)d_in[12];

  char* ws = (char*)d_ws;
  constexpr size_t o_qkvw = 0;                 // 1536*512*2  = 1572864
  constexpr size_t o_projw = 1572864;          // 512*512*2   = 524288
  constexpr size_t o_fc1w  = 2097152;          // 2048*512*2  = 2097152
  constexpr size_t o_fc2w  = 4194304;          // 512*2048*2  = 2097152
  constexpr size_t o_h     = 6291456;          // 8192*512*2  = 8388608
  constexpr size_t o_qkvC  = 14680064;         // 8192*1536*2 = 25165824
  constexpr size_t o_q     = 39845888;         // 8388608
  constexpr size_t o_k     = 48234496;         // 8388608
  constexpr size_t o_vt    = 56623104;         // 8388608
  constexpr size_t o_attn  = 65011712;         // 8388608
  constexpr size_t o_x2    = 73400320;         // 8192*512*4  = 16777216
  constexpr size_t o_fc1o  = o_qkvC;           // 8192*2048*2 = 33554432 (reuses dead qkvC+q)
  constexpr size_t needed  = 90177536;
  if (ws_size < needed) return;

  bf16* qkvw_bf = (bf16*)(ws + o_qkvw);
  bf16* projw_bf = (bf16*)(ws + o_projw);
  bf16* fc1w_bf = (bf16*)(ws + o_fc1w);
  bf16* fc2w_bf = (bf16*)(ws + o_fc2w);
  bf16* h    = (bf16*)(ws + o_h);
  bf16* qkvC = (bf16*)(ws + o_qkvC);
  bf16* q    = (bf16*)(ws + o_q);
  bf16* k    = (bf16*)(ws + o_k);
  bf16* vt   = (bf16*)(ws + o_vt);
  bf16* attn = (bf16*)(ws + o_attn);
  float* x2  = (float*)(ws + o_x2);
  bf16* fc1o = (bf16*)(ws + o_fc1o);
  float* out = (float*)d_out;

  cvt_f32_bf16<<<768, 256, 0, stream>>>(qkv_w, qkvw_bf, 786432 / 4);
  cvt_f32_bf16<<<256, 256, 0, stream>>>(proj_w, projw_bf, 262144 / 4);
  cvt_f32_bf16<<<1024, 256, 0, stream>>>(fc1_w, fc1w_bf, 1048576 / 4);
  cvt_f32_bf16<<<1024, 256, 0, stream>>>(fc2_w, fc2w_bf, 1048576 / 4);

  ln_kernel<<<2048, 256, 0, stream>>>(x, ln1_g, ln1_b, h);
  gemm_bt<0><<<dim3(64, 12), 256, 0, stream>>>(h, qkvw_bf, qkv_b, nullptr, qkvC, 8192, 1536, 512);
  reshape_qkv<<<dim3(64, 16), 256, 0, stream>>>(qkvC, q, k, vt);
  attn_kernel<<<dim3(32, 16), 256, 0, stream>>>(q, k, vt, attn);
  gemm_bt<2><<<dim3(64, 4), 256, 0, stream>>>(attn, projw_bf, proj_b, x, x2, 8192, 512, 512);
  ln_kernel<<<2048, 256, 0, stream>>>(x2, ln2_g, ln2_b, h);
  gemm_bt<1><<<dim3(64, 16), 256, 0, stream>>>(h, fc1w_bf, fc1_b, nullptr, fc1o, 8192, 2048, 512);
  gemm_bt<2><<<dim3(64, 4), 256, 0, stream>>>(fc1o, fc2w_bf, fc2_b, x2, out, 8192, 512, 2048);
}

// Round 2
// 329.835 us; speedup vs baseline: 1.2802x; 1.2802x over previous
//
#include <hip/hip_runtime.h>
#include <hip/hip_bf16.h>

using bf16 = __hip_bfloat16;
typedef __attribute__((ext_vector_type(8))) short short8;   // 8 x bf16 (4 VGPRs) MFMA A/B frag
typedef __attribute__((ext_vector_type(4))) float f32x4;    // MFMA C/D frag

#define GAS __attribute__((address_space(1)))
#define LAS __attribute__((address_space(3)))

__device__ __forceinline__ void gld_lds16(const void* g, void* l) {
  __builtin_amdgcn_global_load_lds((const GAS void*)g, (LAS void*)l, 16, 0, 0);
}

__device__ __forceinline__ unsigned short f2bfu(float f) {
  bf16 h = __float2bfloat16(f);
  return *reinterpret_cast<unsigned short*>(&h);
}

// ---------------- weight f32 -> bf16 ----------------
__global__ __launch_bounds__(256) void cvt_f32_bf16(const float* __restrict__ in,
                                                    bf16* __restrict__ out, int n4) {
  int i = blockIdx.x * 256 + threadIdx.x;
  if (i >= n4) return;
  float4 v = reinterpret_cast<const float4*>(in)[i];
  ushort4 o;
  o.x = f2bfu(v.x); o.y = f2bfu(v.y); o.z = f2bfu(v.z); o.w = f2bfu(v.w);
  reinterpret_cast<ushort4*>(out)[i] = o;
}

// ---------------- LayerNorm (fp32 in, bf16 out), one wave per 512-row ----------------
__global__ __launch_bounds__(256) void ln_kernel(const float* __restrict__ x,
                                                 const float* __restrict__ g,
                                                 const float* __restrict__ b,
                                                 bf16* __restrict__ out) {
  const int row = blockIdx.x * 4 + (threadIdx.x >> 6);
  const int lane = threadIdx.x & 63;
  const float4* xr = reinterpret_cast<const float4*>(x + (size_t)row * 512);
  float4 v0 = xr[lane], v1 = xr[64 + lane];
  float s  = v0.x + v0.y + v0.z + v0.w + v1.x + v1.y + v1.z + v1.w;
  float s2 = v0.x*v0.x + v0.y*v0.y + v0.z*v0.z + v0.w*v0.w
           + v1.x*v1.x + v1.y*v1.y + v1.z*v1.z + v1.w*v1.w;
  #pragma unroll
  for (int d = 1; d < 64; d <<= 1) { s += __shfl_xor(s, d); s2 += __shfl_xor(s2, d); }
  const float mu = s * (1.0f / 512.0f);
  const float var = s2 * (1.0f / 512.0f) - mu * mu;
  const float rstd = rsqrtf(var + 1e-5f);
  const float4* g4 = reinterpret_cast<const float4*>(g);
  const float4* b4 = reinterpret_cast<const float4*>(b);
  float4 ga = g4[lane], gb = g4[64 + lane], ba = b4[lane], bb = b4[64 + lane];
  ushort4 o0, o1;
  o0.x = f2bfu((v0.x - mu) * rstd * ga.x + ba.x);
  o0.y = f2bfu((v0.y - mu) * rstd * ga.y + ba.y);
  o0.z = f2bfu((v0.z - mu) * rstd * ga.z + ba.z);
  o0.w = f2bfu((v0.w - mu) * rstd * ga.w + ba.w);
  o1.x = f2bfu((v1.x - mu) * rstd * gb.x + bb.x);
  o1.y = f2bfu((v1.y - mu) * rstd * gb.y + bb.y);
  o1.z = f2bfu((v1.z - mu) * rstd * gb.z + bb.z);
  o1.w = f2bfu((v1.w - mu) * rstd * gb.w + bb.w);
  ushort4* orow = reinterpret_cast<ushort4*>(out + (size_t)row * 512);
  orow[lane] = o0;
  orow[64 + lane] = o1;
}

// ---------------- GEMM: C[M,N] = A[M,K] * B[N,K]^T (+bias, epilogue) ----------------
template <int EPI>
__global__ __launch_bounds__(256) void gemm_bt(const bf16* __restrict__ A,
                                               const bf16* __restrict__ B,
                                               const float* __restrict__ bias,
                                               const float* __restrict__ resid,
                                               void* __restrict__ Cv,
                                               int M, int N, int K) {
  __shared__ bf16 As[128 * 32];
  __shared__ bf16 Bs[128 * 32];
  const int tid = threadIdx.x;
  const int lane = tid & 63, wid = tid >> 6;
  const int lr = lane & 15, lg = lane >> 4;
  const int row0 = blockIdx.x * 128, col0 = blockIdx.y * 128;
  const int wr = (wid >> 1) * 64, wc = (wid & 1) * 64;
  f32x4 acc[4][4] = {};
  const int r1 = tid >> 2,          c1 = (tid & 3) * 8;
  const int r2 = (256 + tid) >> 2,  c2 = ((256 + tid) & 3) * 8;
  for (int kt = 0; kt < K; kt += 32) {
    __syncthreads();
    gld_lds16(A + (size_t)(row0 + r1) * K + kt + c1, As + tid * 8);
    gld_lds16(A + (size_t)(row0 + r2) * K + kt + c2, As + (256 + tid) * 8);
    gld_lds16(B + (size_t)(col0 + r1) * K + kt + c1, Bs + tid * 8);
    gld_lds16(B + (size_t)(col0 + r2) * K + kt + c2, Bs + (256 + tid) * 8);
    __syncthreads();
    short8 af[4], bfr[4];
    #pragma unroll
    for (int mi = 0; mi < 4; ++mi)
      af[mi] = *reinterpret_cast<const short8*>(&As[(wr + mi * 16 + lr) * 32 + lg * 8]);
    #pragma unroll
    for (int nj = 0; nj < 4; ++nj)
      bfr[nj] = *reinterpret_cast<const short8*>(&Bs[(wc + nj * 16 + lr) * 32 + lg * 8]);
    #pragma unroll
    for (int mi = 0; mi < 4; ++mi)
      #pragma unroll
      for (int nj = 0; nj < 4; ++nj)
        acc[mi][nj] = __builtin_amdgcn_mfma_f32_16x16x32_bf16(af[mi], bfr[nj], acc[mi][nj], 0, 0, 0);
  }
  #pragma unroll
  for (int mi = 0; mi < 4; ++mi) {
    #pragma unroll
    for (int nj = 0; nj < 4; ++nj) {
      const int col = col0 + wc + nj * 16 + lr;
      const float bv = bias ? bias[col] : 0.0f;
      #pragma unroll
      for (int rg = 0; rg < 4; ++rg) {
        const int row = row0 + wr + mi * 16 + lg * 4 + rg;
        float v = acc[mi][nj][rg] + bv;
        if constexpr (EPI == 1) v = 0.5f * v * (1.0f + erff(v * 0.70710678118654752f));
        if constexpr (EPI == 2) {
          reinterpret_cast<float*>(Cv)[(size_t)row * N + col] = v + resid[(size_t)row * N + col];
        } else {
          reinterpret_cast<bf16*>(Cv)[(size_t)row * N + col] = __float2bfloat16(v);
        }
      }
    }
  }
}

// ---------------- reshape QKV ----------------
__global__ __launch_bounds__(256) void reshape_qkv(const bf16* __restrict__ C,
                                                   bf16* __restrict__ q,
                                                   bf16* __restrict__ k,
                                                   bf16* __restrict__ vt) {
  const int nt = blockIdx.x;
  const int bh = blockIdx.y;
  const int b = bh >> 3, h = bh & 7;
  __shared__ bf16 vs[64][65];
  const int tid = threadIdx.x;
  #pragma unroll
  for (int i = 0; i < 16; ++i) {
    const int idx = i * 256 + tid;
    const int rr = idx >> 6, c = idx & 63;
    const size_t crow = ((size_t)b * 4096 + nt * 64 + rr) * 1536;
    const size_t onb = ((size_t)bh * 4096 + nt * 64 + rr) * 64 + c;
    q[onb] = __float2bfloat16(__bfloat162float(C[crow + h * 64 + c]) * 0.125f);
    k[onb] = C[crow + 512 + h * 64 + c];
    vs[rr][c] = C[crow + 1024 + h * 64 + c];
  }
  __syncthreads();
  #pragma unroll
  for (int i = 0; i < 16; ++i) {
    const int idx = i * 256 + tid;
    const int d = idx >> 6, n = idx & 63;
    vt[((size_t)bh * 64 + d) * 4096 + nt * 64 + n] = vs[n][d];
  }
}

// ---------------- flash attention (swapped-MFMA, XOR-swizzled LDS, dbuf KV) ----------------
// Q[BH,N,64] (pre-scaled), K[BH,N,64], Vt[BH,64,N] -> Out[B,N,512] bf16
// Per block: 128 q-rows (4 waves x 32), KV tiles of 64, NT=64 iterations.
__device__ __forceinline__ short8 lds_swz_read(const char* base, int row, int colb) {
  const int off = (row * 128 + colb) ^ ((row & 7) << 4);
  return *reinterpret_cast<const short8*>(base + off);
}

__global__ __launch_bounds__(256) void attn_kernel(const bf16* __restrict__ Q,
                                                   const bf16* __restrict__ K,
                                                   const bf16* __restrict__ Vt,
                                                   bf16* __restrict__ Out) {
  const int qt = blockIdx.x;   // 0..31
  const int bh = blockIdx.y;   // 0..15
  const int b = bh >> 3, h = bh & 7;
  __shared__ bf16 QP[8192];       // 16KB: Q tile [128][64] swz; reused as P after Q->regs
  __shared__ bf16 Ks[2][4096];    // 2 x 8KB [64][64] swz
  __shared__ bf16 Vs[2][4096];    // 2 x 8KB [64][64] swz (rows = d)
  const int tid = threadIdx.x, wid = tid >> 6, lane = tid & 63;
  const int lr = lane & 15, lg = lane >> 4;
  const char* Qg = (const char*)(Q + ((size_t)bh * 4096 + qt * 128) * 64);
  const char* Kg = (const char*)(K + (size_t)bh * 4096 * 64);
  const char* Vg = (const char*)(Vt + (size_t)bh * 64 * 4096);

  // ---- stage Q (pre-swizzled source, linear LDS dest) ----
  #pragma unroll
  for (int i = 0; i < 4; ++i) {
    const int ph = (i * 256 + tid) * 16;
    const int row = ph >> 7;
    const int lb = ph ^ ((row & 7) << 4);
    gld_lds16(Qg + lb, (char*)QP + ph);
  }
  __syncthreads();
  // ---- Q frags -> registers (B operand: rows = q) ----
  short8 bq[2][2];
  #pragma unroll
  for (int mi = 0; mi < 2; ++mi)
    #pragma unroll
    for (int kk = 0; kk < 2; ++kk)
      bq[mi][kk] = lds_swz_read((const char*)QP, wid * 32 + mi * 16 + lr, kk * 64 + lg * 16);
  // wave-private P region (reuses QP): [16 q][64 kv] bf16, swizzled rows
  char* Pw = (char*)QP + wid * 4096;

  f32x4 Oa[2][4] = {};
  float mrow[2] = {-1e30f, -1e30f}, lrow[2] = {0.0f, 0.0f};

  // ---- stage KV tile 0 into buf 0 ----
  #pragma unroll
  for (int i = 0; i < 2; ++i) {
    const int ph = (i * 256 + tid) * 16;
    const int row = ph >> 7;
    const int lb = ph ^ ((row & 7) << 4);
    gld_lds16(Kg + lb, (char*)Ks[0] + ph);
    gld_lds16(Vg + row * 8192 + (lb & 127), (char*)Vs[0] + ph);
  }

  int cur = 0;
  for (int t = 0; t < 64; ++t) {
    __syncthreads();   // stage(t) complete; buf cur^1 free (consumed in t-1)
    if (t + 1 < 64) {
      const char* Kt = Kg + (size_t)(t + 1) * 8192;
      #pragma unroll
      for (int i = 0; i < 2; ++i) {
        const int ph = (i * 256 + tid) * 16;
        const int row = ph >> 7;
        const int lb = ph ^ ((row & 7) << 4);
        gld_lds16(Kt + lb, (char*)Ks[cur ^ 1] + ph);
        gld_lds16(Vg + row * 8192 + (t + 1) * 128 + (lb & 127), (char*)Vs[cur ^ 1] + ph);
      }
    }
    const char* ksb = (const char*)Ks[cur];
    const char* vsb = (const char*)Vs[cur];
    // ---- K frags (A operand: rows = kv) ----
    short8 ak[4][2];
    #pragma unroll
    for (int nk = 0; nk < 4; ++nk)
      #pragma unroll
      for (int kk = 0; kk < 2; ++kk)
        ak[nk][kk] = lds_swz_read(ksb, nk * 16 + lr, kk * 64 + lg * 16);

    #pragma unroll
    for (int mi = 0; mi < 2; ++mi) {
      // S^T = K . Q^T : lane holds S[q=lr][kv = nk*16 + lg*4 + rg]
      f32x4 Sa[4];
      #pragma unroll
      for (int nk = 0; nk < 4; ++nk) {
        f32x4 z = {0.0f, 0.0f, 0.0f, 0.0f};
        z = __builtin_amdgcn_mfma_f32_16x16x32_bf16(ak[nk][0], bq[mi][0], z, 0, 0, 0);
        Sa[nk] = __builtin_amdgcn_mfma_f32_16x16x32_bf16(ak[nk][1], bq[mi][1], z, 0, 0, 0);
      }
      // ---- online softmax: row q=lr spans 4 lanes (lg) x 16 values ----
      float rmax = Sa[0][0];
      #pragma unroll
      for (int nk = 0; nk < 4; ++nk)
        #pragma unroll
        for (int rg = 0; rg < 4; ++rg) rmax = fmaxf(rmax, Sa[nk][rg]);
      rmax = fmaxf(rmax, __shfl_xor(rmax, 16));
      rmax = fmaxf(rmax, __shfl_xor(rmax, 32));
      const float mnew = fmaxf(mrow[mi], rmax);
      const float fsc = __expf(mrow[mi] - mnew);
      float rsum = 0.0f;
      #pragma unroll
      for (int nk = 0; nk < 4; ++nk)
        #pragma unroll
        for (int rg = 0; rg < 4; ++rg) {
          const float p = __expf(Sa[nk][rg] - mnew);
          Sa[nk][rg] = p;
          rsum += p;
        }
      rsum += __shfl_xor(rsum, 16);
      rsum += __shfl_xor(rsum, 32);
      lrow[mi] = lrow[mi] * fsc + rsum;
      mrow[mi] = mnew;
      #pragma unroll
      for (int db = 0; db < 4; ++db)
        #pragma unroll
        for (int e = 0; e < 4; ++e) Oa[mi][db][e] *= fsc;
      // ---- P -> LDS (swizzled u32 writes), region [16 q][64 kv] per wave ----
      char* pm = Pw + mi * 2048;
      #pragma unroll
      for (int nk = 0; nk < 4; ++nk)
        #pragma unroll
        for (int hh = 0; hh < 2; ++hh) {
          const unsigned int pk =
              (unsigned int)f2bfu(Sa[nk][2 * hh]) |
              ((unsigned int)f2bfu(Sa[nk][2 * hh + 1]) << 16);
          const int off = (lr * 128 + nk * 32 + lg * 8 + hh * 4) ^ ((lr & 7) << 4);
          *reinterpret_cast<unsigned int*>(pm + off) = pk;
        }
    }
    // ---- V frags (A operand: rows = d) ----
    short8 av[4][2];
    #pragma unroll
    for (int db = 0; db < 4; ++db)
      #pragma unroll
      for (int kk = 0; kk < 2; ++kk)
        av[db][kk] = lds_swz_read(vsb, db * 16 + lr, kk * 64 + lg * 16);
    // ---- O^T += Vt . P^T : lane holds O[q=lr][d = db*16 + lg*4 + rg] ----
    #pragma unroll
    for (int mi = 0; mi < 2; ++mi) {
      const char* pm = Pw + mi * 2048;
      short8 bp0 = lds_swz_read(pm, lr, lg * 16);
      short8 bp1 = lds_swz_read(pm, lr, 64 + lg * 16);
      #pragma unroll
      for (int db = 0; db < 4; ++db) {
        Oa[mi][db] = __builtin_amdgcn_mfma_f32_16x16x32_bf16(av[db][0], bp0, Oa[mi][db], 0, 0, 0);
        Oa[mi][db] = __builtin_amdgcn_mfma_f32_16x16x32_bf16(av[db][1], bp1, Oa[mi][db], 0, 0, 0);
      }
    }
    cur ^= 1;
  }
  // ---- normalize + store: lane q=lr, d = db*16 + lg*4 + rg ----
  #pragma unroll
  for (int mi = 0; mi < 2; ++mi) {
    const float linv = 1.0f / lrow[mi];
    const int n = qt * 128 + wid * 32 + mi * 16 + lr;
    #pragma unroll
    for (int db = 0; db < 4; ++db) {
      ushort4 o;
      o.x = f2bfu(Oa[mi][db][0] * linv);
      o.y = f2bfu(Oa[mi][db][1] * linv);
      o.z = f2bfu(Oa[mi][db][2] * linv);
      o.w = f2bfu(Oa[mi][db][3] * linv);
      *reinterpret_cast<ushort4*>(Out + ((size_t)b * 4096 + n) * 512 + h * 64 + db * 16 + lg * 4) = o;
    }
  }
}

// ---------------- host ----------------
extern "C" void kernel_launch(void* const* d_in, const int* in_sizes, int n_in,
                              void* d_out, int out_size, void* d_ws, size_t ws_size,
                              hipStream_t stream) {
  const float* x      = (const float*)d_in[0];
  const float* ln1_g  = (const float*)d_in[1];
  const float* ln1_b  = (const float*)d_in[2];
  const float* ln2_g  = (const float*)d_in[3];
  const float* ln2_b  = (const float*)d_in[4];
  const float* qkv_w  = (const float*)d_in[5];
  const float* qkv_b  = (const float*)d_in[6];
  const float* proj_w = (const float*)d_in[7];
  const float* proj_b = (const float*)d_in[8];
  const float* fc1_w  = (const float*)d_in[9];
  const float* fc1_b  = (const float*)d_in[10];
  const float* fc2_w  = (const float*)d_in[11];
  const float* fc2_b  = (const float*)d_in[12];

  char* ws = (char*)d_ws;
  constexpr size_t o_qkvw = 0;
  constexpr size_t o_projw = 1572864;
  constexpr size_t o_fc1w  = 2097152;
  constexpr size_t o_fc2w  = 4194304;
  constexpr size_t o_h     = 6291456;
  constexpr size_t o_qkvC  = 14680064;
  constexpr size_t o_q     = 39845888;
  constexpr size_t o_k     = 48234496;
  constexpr size_t o_vt    = 56623104;
  constexpr size_t o_attn  = 65011712;
  constexpr size_t o_x2    = 73400320;
  constexpr size_t o_fc1o  = o_qkvC;
  constexpr size_t needed  = 90177536;
  if (ws_size < needed) return;

  bf16* qkvw_bf = (bf16*)(ws + o_qkvw);
  bf16* projw_bf = (bf16*)(ws + o_projw);
  bf16* fc1w_bf = (bf16*)(ws + o_fc1w);
  bf16* fc2w_bf = (bf16*)(ws + o_fc2w);
  bf16* h    = (bf16*)(ws + o_h);
  bf16* qkvC = (bf16*)(ws + o_qkvC);
  bf16* q    = (bf16*)(ws + o_q);
  bf16* k    = (bf16*)(ws + o_k);
  bf16* vt   = (bf16*)(ws + o_vt);
  bf16* attn = (bf16*)(ws + o_attn);
  float* x2  = (float*)(ws + o_x2);
  bf16* fc1o = (bf16*)(ws + o_fc1o);
  float* out = (float*)d_out;

  cvt_f32_bf16<<<768, 256, 0, stream>>>(qkv_w, qkvw_bf, 786432 / 4);
  cvt_f32_bf16<<<256, 256, 0, stream>>>(proj_w, projw_bf, 262144 / 4);
  cvt_f32_bf16<<<1024, 256, 0, stream>>>(fc1_w, fc1w_bf, 1048576 / 4);
  cvt_f32_bf16<<<1024, 256, 0, stream>>>(fc2_w, fc2w_bf, 1048576 / 4);

  ln_kernel<<<2048, 256, 0, stream>>>(x, ln1_g, ln1_b, h);
  gemm_bt<0><<<dim3(64, 12), 256, 0, stream>>>(h, qkvw_bf, qkv_b, nullptr, qkvC, 8192, 1536, 512);
  reshape_qkv<<<dim3(64, 16), 256, 0, stream>>>(qkvC, q, k, vt);
  attn_kernel<<<dim3(32, 16), 256, 0, stream>>>(q, k, vt, attn);
  gemm_bt<2><<<dim3(64, 4), 256, 0, stream>>>(attn, projw_bf, proj_b, x, x2, 8192, 512, 512);
  ln_kernel<<<2048, 256, 0, stream>>>(x2, ln2_g, ln2_b, h);
  gemm_bt<1><<<dim3(64, 16), 256, 0, stream>>>(h, fc1w_bf, fc1_b, nullptr, fc1o, 8192, 2048, 512);
  gemm_bt<2><<<dim3(64, 4), 256, 0, stream>>>(fc1o, fc2w_bf, fc2_b, x2, out, 8192, 512, 2048);
}

// Round 3
// 325.537 us; speedup vs baseline: 1.2971x; 1.0132x over previous
//
#include <hip/hip_runtime.h>
#include <hip/hip_bf16.h>

using bf16 = __hip_bfloat16;
typedef __attribute__((ext_vector_type(8))) short short8;   // 8 x bf16 (4 VGPRs) MFMA A/B frag
typedef __attribute__((ext_vector_type(4))) float f32x4;    // MFMA C/D frag

#define GAS __attribute__((address_space(1)))
#define LAS __attribute__((address_space(3)))

__device__ __forceinline__ void gld_lds16(const void* g, void* l) {
  __builtin_amdgcn_global_load_lds((const GAS void*)g, (LAS void*)l, 16, 0, 0);
}

__device__ __forceinline__ unsigned short f2bfu(float f) {
  bf16 h = __float2bfloat16(f);
  return *reinterpret_cast<unsigned short*>(&h);
}

// ---------------- weight f32 -> bf16 ----------------
__global__ __launch_bounds__(256) void cvt_f32_bf16(const float* __restrict__ in,
                                                    bf16* __restrict__ out, int n4) {
  int i = blockIdx.x * 256 + threadIdx.x;
  if (i >= n4) return;
  float4 v = reinterpret_cast<const float4*>(in)[i];
  ushort4 o;
  o.x = f2bfu(v.x); o.y = f2bfu(v.y); o.z = f2bfu(v.z); o.w = f2bfu(v.w);
  reinterpret_cast<ushort4*>(out)[i] = o;
}

// ---------------- LayerNorm (fp32 in, bf16 out), one wave per 512-row ----------------
__global__ __launch_bounds__(256) void ln_kernel(const float* __restrict__ x,
                                                 const float* __restrict__ g,
                                                 const float* __restrict__ b,
                                                 bf16* __restrict__ out) {
  const int row = blockIdx.x * 4 + (threadIdx.x >> 6);
  const int lane = threadIdx.x & 63;
  const float4* xr = reinterpret_cast<const float4*>(x + (size_t)row * 512);
  float4 v0 = xr[lane], v1 = xr[64 + lane];
  float s  = v0.x + v0.y + v0.z + v0.w + v1.x + v1.y + v1.z + v1.w;
  float s2 = v0.x*v0.x + v0.y*v0.y + v0.z*v0.z + v0.w*v0.w
           + v1.x*v1.x + v1.y*v1.y + v1.z*v1.z + v1.w*v1.w;
  #pragma unroll
  for (int d = 1; d < 64; d <<= 1) { s += __shfl_xor(s, d); s2 += __shfl_xor(s2, d); }
  const float mu = s * (1.0f / 512.0f);
  const float var = s2 * (1.0f / 512.0f) - mu * mu;
  const float rstd = rsqrtf(var + 1e-5f);
  const float4* g4 = reinterpret_cast<const float4*>(g);
  const float4* b4 = reinterpret_cast<const float4*>(b);
  float4 ga = g4[lane], gb = g4[64 + lane], ba = b4[lane], bb = b4[64 + lane];
  ushort4 o0, o1;
  o0.x = f2bfu((v0.x - mu) * rstd * ga.x + ba.x);
  o0.y = f2bfu((v0.y - mu) * rstd * ga.y + ba.y);
  o0.z = f2bfu((v0.z - mu) * rstd * ga.z + ba.z);
  o0.w = f2bfu((v0.w - mu) * rstd * ga.w + ba.w);
  o1.x = f2bfu((v1.x - mu) * rstd * gb.x + bb.x);
  o1.y = f2bfu((v1.y - mu) * rstd * gb.y + bb.y);
  o1.z = f2bfu((v1.z - mu) * rstd * gb.z + bb.z);
  o1.w = f2bfu((v1.w - mu) * rstd * gb.w + bb.w);
  ushort4* orow = reinterpret_cast<ushort4*>(out + (size_t)row * 512);
  orow[lane] = o0;
  orow[64 + lane] = o1;
}

// ---------------- GEMM: C[M,N] = A[M,K] * B[N,K]^T (+bias, epilogue) ----------------
template <int EPI>
__global__ __launch_bounds__(256) void gemm_bt(const bf16* __restrict__ A,
                                               const bf16* __restrict__ B,
                                               const float* __restrict__ bias,
                                               const float* __restrict__ resid,
                                               void* __restrict__ Cv,
                                               int M, int N, int K) {
  __shared__ bf16 As[128 * 32];
  __shared__ bf16 Bs[128 * 32];
  const int tid = threadIdx.x;
  const int lane = tid & 63, wid = tid >> 6;
  const int lr = lane & 15, lg = lane >> 4;
  const int row0 = blockIdx.x * 128, col0 = blockIdx.y * 128;
  const int wr = (wid >> 1) * 64, wc = (wid & 1) * 64;
  f32x4 acc[4][4] = {};
  const int r1 = tid >> 2,          c1 = (tid & 3) * 8;
  const int r2 = (256 + tid) >> 2,  c2 = ((256 + tid) & 3) * 8;
  for (int kt = 0; kt < K; kt += 32) {
    __syncthreads();
    gld_lds16(A + (size_t)(row0 + r1) * K + kt + c1, As + tid * 8);
    gld_lds16(A + (size_t)(row0 + r2) * K + kt + c2, As + (256 + tid) * 8);
    gld_lds16(B + (size_t)(col0 + r1) * K + kt + c1, Bs + tid * 8);
    gld_lds16(B + (size_t)(col0 + r2) * K + kt + c2, Bs + (256 + tid) * 8);
    __syncthreads();
    short8 af[4], bfr[4];
    #pragma unroll
    for (int mi = 0; mi < 4; ++mi)
      af[mi] = *reinterpret_cast<const short8*>(&As[(wr + mi * 16 + lr) * 32 + lg * 8]);
    #pragma unroll
    for (int nj = 0; nj < 4; ++nj)
      bfr[nj] = *reinterpret_cast<const short8*>(&Bs[(wc + nj * 16 + lr) * 32 + lg * 8]);
    #pragma unroll
    for (int mi = 0; mi < 4; ++mi)
      #pragma unroll
      for (int nj = 0; nj < 4; ++nj)
        acc[mi][nj] = __builtin_amdgcn_mfma_f32_16x16x32_bf16(af[mi], bfr[nj], acc[mi][nj], 0, 0, 0);
  }
  #pragma unroll
  for (int mi = 0; mi < 4; ++mi) {
    #pragma unroll
    for (int nj = 0; nj < 4; ++nj) {
      const int col = col0 + wc + nj * 16 + lr;
      const float bv = bias ? bias[col] : 0.0f;
      #pragma unroll
      for (int rg = 0; rg < 4; ++rg) {
        const int row = row0 + wr + mi * 16 + lg * 4 + rg;
        float v = acc[mi][nj][rg] + bv;
        if constexpr (EPI == 1) v = 0.5f * v * (1.0f + erff(v * 0.70710678118654752f));
        if constexpr (EPI == 2) {
          reinterpret_cast<float*>(Cv)[(size_t)row * N + col] = v + resid[(size_t)row * N + col];
        } else {
          reinterpret_cast<bf16*>(Cv)[(size_t)row * N + col] = __float2bfloat16(v);
        }
      }
    }
  }
}

// ---------------- reshape QKV (q pre-scaled by 0.125*log2e for exp2-domain softmax) ----------------
__global__ __launch_bounds__(256) void reshape_qkv(const bf16* __restrict__ C,
                                                   bf16* __restrict__ q,
                                                   bf16* __restrict__ k,
                                                   bf16* __restrict__ vt) {
  const int nt = blockIdx.x;
  const int bh = blockIdx.y;
  const int b = bh >> 3, h = bh & 7;
  __shared__ bf16 vs[64][65];
  const int tid = threadIdx.x;
  const float qs = 0.125f * 1.44269504088896340736f;
  #pragma unroll
  for (int i = 0; i < 16; ++i) {
    const int idx = i * 256 + tid;
    const int rr = idx >> 6, c = idx & 63;
    const size_t crow = ((size_t)b * 4096 + nt * 64 + rr) * 1536;
    const size_t onb = ((size_t)bh * 4096 + nt * 64 + rr) * 64 + c;
    q[onb] = __float2bfloat16(__bfloat162float(C[crow + h * 64 + c]) * qs);
    k[onb] = C[crow + 512 + h * 64 + c];
    vs[rr][c] = C[crow + 1024 + h * 64 + c];
  }
  __syncthreads();
  #pragma unroll
  for (int i = 0; i < 16; ++i) {
    const int idx = i * 256 + tid;
    const int d = idx >> 6, n = idx & 63;
    vt[((size_t)bh * 64 + d) * 4096 + nt * 64 + n] = vs[n][d];
  }
}

// ---------------- flash attention: QBLK=64 (1 wave = 16 q-rows), exp2 softmax, defer-max ----------------
__device__ __forceinline__ short8 lds_swz_read(const char* base, int row, int colb) {
  const int off = (row * 128 + colb) ^ ((row & 7) << 4);
  return *reinterpret_cast<const short8*>(base + off);
}

__global__ __launch_bounds__(256, 4) void attn_kernel(const bf16* __restrict__ Q,
                                                      const bf16* __restrict__ K,
                                                      const bf16* __restrict__ Vt,
                                                      bf16* __restrict__ Out) {
  const int qt = blockIdx.x;   // 0..63 (64 q rows each)
  const int bh = blockIdx.y;   // 0..15
  const int b = bh >> 3, h = bh & 7;
  __shared__ bf16 QP[4096];       // 8KB: Q tile [64][64] swz; reused as P (4 x 2KB per wave)
  __shared__ bf16 Ks[2][4096];    // 2 x 8KB [64 kv][64 d] swz
  __shared__ bf16 Vs[2][4096];    // 2 x 8KB [64 d][64 kv] swz
  const int tid = threadIdx.x, wid = tid >> 6, lane = tid & 63;
  const int lr = lane & 15, lg = lane >> 4;
  const char* Qg = (const char*)(Q + ((size_t)bh * 4096 + qt * 64) * 64);
  const char* Kg = (const char*)(K + (size_t)bh * 4096 * 64);
  const char* Vg = (const char*)(Vt + (size_t)bh * 64 * 4096);

  // ---- stage Q (pre-swizzled source, linear LDS dest) ----
  #pragma unroll
  for (int i = 0; i < 2; ++i) {
    const int ph = (i * 256 + tid) * 16;
    const int row = ph >> 7;
    const int lb = ph ^ ((row & 7) << 4);
    gld_lds16(Qg + lb, (char*)QP + ph);
  }
  __syncthreads();
  // ---- Q frags -> registers (B operand: rows = q) ----
  short8 bq[2];
  #pragma unroll
  for (int kk = 0; kk < 2; ++kk)
    bq[kk] = lds_swz_read((const char*)QP, wid * 16 + lr, kk * 64 + lg * 16);
  // wave-private P region (reuses QP): [16 q][64 kv] bf16, swizzled rows
  char* Pw = (char*)QP + wid * 2048;

  f32x4 Oa[4] = {};
  float mrow = -1e30f, lrow = 0.0f;

  // ---- stage KV tile 0 into buf 0 ----
  #pragma unroll
  for (int i = 0; i < 2; ++i) {
    const int ph = (i * 256 + tid) * 16;
    const int row = ph >> 7;
    const int lb = ph ^ ((row & 7) << 4);
    gld_lds16(Kg + lb, (char*)Ks[0] + ph);
    gld_lds16(Vg + row * 8192 + (lb & 127), (char*)Vs[0] + ph);
  }

  int cur = 0;
  for (int t = 0; t < 64; ++t) {
    __syncthreads();   // stage(t) complete; buf cur^1 free
    if (t + 1 < 64) {
      const char* Kt = Kg + (size_t)(t + 1) * 8192;
      #pragma unroll
      for (int i = 0; i < 2; ++i) {
        const int ph = (i * 256 + tid) * 16;
        const int row = ph >> 7;
        const int lb = ph ^ ((row & 7) << 4);
        gld_lds16(Kt + lb, (char*)Ks[cur ^ 1] + ph);
        gld_lds16(Vg + row * 8192 + (t + 1) * 128 + (lb & 127), (char*)Vs[cur ^ 1] + ph);
      }
    }
    const char* ksb = (const char*)Ks[cur];
    const char* vsb = (const char*)Vs[cur];
    // ---- K frags (A operand: rows = kv) ----
    short8 ak[4][2];
    #pragma unroll
    for (int nk = 0; nk < 4; ++nk)
      #pragma unroll
      for (int kk = 0; kk < 2; ++kk)
        ak[nk][kk] = lds_swz_read(ksb, nk * 16 + lr, kk * 64 + lg * 16);
    // ---- S^T = K . Q^T : lane holds S[q=lr][kv = nk*16 + lg*4 + rg] (log2 domain) ----
    f32x4 Sa[4];
    __builtin_amdgcn_s_setprio(1);
    #pragma unroll
    for (int nk = 0; nk < 4; ++nk) {
      f32x4 z = {0.0f, 0.0f, 0.0f, 0.0f};
      z = __builtin_amdgcn_mfma_f32_16x16x32_bf16(ak[nk][0], bq[0], z, 0, 0, 0);
      Sa[nk] = __builtin_amdgcn_mfma_f32_16x16x32_bf16(ak[nk][1], bq[1], z, 0, 0, 0);
    }
    __builtin_amdgcn_s_setprio(0);
    // ---- online softmax (tree reduce; defer-max with THR=8 in log2 units) ----
    float t0 = fmaxf(fmaxf(Sa[0][0], Sa[0][1]), fmaxf(Sa[0][2], Sa[0][3]));
    float t1 = fmaxf(fmaxf(Sa[1][0], Sa[1][1]), fmaxf(Sa[1][2], Sa[1][3]));
    float t2 = fmaxf(fmaxf(Sa[2][0], Sa[2][1]), fmaxf(Sa[2][2], Sa[2][3]));
    float t3 = fmaxf(fmaxf(Sa[3][0], Sa[3][1]), fmaxf(Sa[3][2], Sa[3][3]));
    float rmax = fmaxf(fmaxf(t0, t1), fmaxf(t2, t3));
    rmax = fmaxf(rmax, __shfl_xor(rmax, 16));
    rmax = fmaxf(rmax, __shfl_xor(rmax, 32));
    if (!__all(rmax <= mrow + 8.0f)) {
      const float mnew = fmaxf(mrow, rmax);
      const float fsc = exp2f(mrow - mnew);
      lrow *= fsc;
      #pragma unroll
      for (int db = 0; db < 4; ++db)
        #pragma unroll
        for (int e = 0; e < 4; ++e) Oa[db][e] *= fsc;
      mrow = mnew;
    }
    #pragma unroll
    for (int nk = 0; nk < 4; ++nk)
      #pragma unroll
      for (int rg = 0; rg < 4; ++rg) Sa[nk][rg] = exp2f(Sa[nk][rg] - mrow);
    float s0 = (Sa[0][0] + Sa[0][1]) + (Sa[0][2] + Sa[0][3]);
    float s1 = (Sa[1][0] + Sa[1][1]) + (Sa[1][2] + Sa[1][3]);
    float s2 = (Sa[2][0] + Sa[2][1]) + (Sa[2][2] + Sa[2][3]);
    float s3 = (Sa[3][0] + Sa[3][1]) + (Sa[3][2] + Sa[3][3]);
    float rsum = (s0 + s1) + (s2 + s3);
    rsum += __shfl_xor(rsum, 16);
    rsum += __shfl_xor(rsum, 32);
    lrow += rsum;
    // ---- P -> LDS (swizzled u32 writes), [16 q][64 kv] per wave ----
    #pragma unroll
    for (int nk = 0; nk < 4; ++nk)
      #pragma unroll
      for (int hh = 0; hh < 2; ++hh) {
        const unsigned int pk =
            (unsigned int)f2bfu(Sa[nk][2 * hh]) |
            ((unsigned int)f2bfu(Sa[nk][2 * hh + 1]) << 16);
        const int off = (lr * 128 + nk * 32 + lg * 8 + hh * 4) ^ ((lr & 7) << 4);
        *reinterpret_cast<unsigned int*>(Pw + off) = pk;
      }
    // ---- V frags (A operand: rows = d) ----
    short8 av[4][2];
    #pragma unroll
    for (int db = 0; db < 4; ++db)
      #pragma unroll
      for (int kk = 0; kk < 2; ++kk)
        av[db][kk] = lds_swz_read(vsb, db * 16 + lr, kk * 64 + lg * 16);
    short8 bp0 = lds_swz_read(Pw, lr, lg * 16);
    short8 bp1 = lds_swz_read(Pw, lr, 64 + lg * 16);
    // ---- O^T += Vt . P^T : lane holds O[q=lr][d = db*16 + lg*4 + rg] ----
    __builtin_amdgcn_s_setprio(1);
    #pragma unroll
    for (int db = 0; db < 4; ++db) {
      Oa[db] = __builtin_amdgcn_mfma_f32_16x16x32_bf16(av[db][0], bp0, Oa[db], 0, 0, 0);
      Oa[db] = __builtin_amdgcn_mfma_f32_16x16x32_bf16(av[db][1], bp1, Oa[db], 0, 0, 0);
    }
    __builtin_amdgcn_s_setprio(0);
    cur ^= 1;
  }
  // ---- normalize + store: lane q=lr, d = db*16 + lg*4 + rg ----
  const float linv = 1.0f / lrow;
  const int n = qt * 64 + wid * 16 + lr;
  #pragma unroll
  for (int db = 0; db < 4; ++db) {
    ushort4 o;
    o.x = f2bfu(Oa[db][0] * linv);
    o.y = f2bfu(Oa[db][1] * linv);
    o.z = f2bfu(Oa[db][2] * linv);
    o.w = f2bfu(Oa[db][3] * linv);
    *reinterpret_cast<ushort4*>(Out + ((size_t)b * 4096 + n) * 512 + h * 64 + db * 16 + lg * 4) = o;
  }
}

// ---------------- host ----------------
extern "C" void kernel_launch(void* const* d_in, const int* in_sizes, int n_in,
                              void* d_out, int out_size, void* d_ws, size_t ws_size,
                              hipStream_t stream) {
  const float* x      = (const float*)d_in[0];
  const float* ln1_g  = (const float*)d_in[1];
  const float* ln1_b  = (const float*)d_in[2];
  const float* ln2_g  = (const float*)d_in[3];
  const float* ln2_b  = (const float*)d_in[4];
  const float* qkv_w  = (const float*)d_in[5];
  const float* qkv_b  = (const float*)d_in[6];
  const float* proj_w = (const float*)d_in[7];
  const float* proj_b = (const float*)d_in[8];
  const float* fc1_w  = (const float*)d_in[9];
  const float* fc1_b  = (const float*)d_in[10];
  const float* fc2_w  = (const float*)d_in[11];
  const float* fc2_b  = (const float*)d_in[12];

  char* ws = (char*)d_ws;
  constexpr size_t o_qkvw = 0;
  constexpr size_t o_projw = 1572864;
  constexpr size_t o_fc1w  = 2097152;
  constexpr size_t o_fc2w  = 4194304;
  constexpr size_t o_h     = 6291456;
  constexpr size_t o_qkvC  = 14680064;
  constexpr size_t o_q     = 39845888;
  constexpr size_t o_k     = 48234496;
  constexpr size_t o_vt    = 56623104;
  constexpr size_t o_attn  = 65011712;
  constexpr size_t o_x2    = 73400320;
  constexpr size_t o_fc1o  = o_qkvC;
  constexpr size_t needed  = 90177536;
  if (ws_size < needed) return;

  bf16* qkvw_bf = (bf16*)(ws + o_qkvw);
  bf16* projw_bf = (bf16*)(ws + o_projw);
  bf16* fc1w_bf = (bf16*)(ws + o_fc1w);
  bf16* fc2w_bf = (bf16*)(ws + o_fc2w);
  bf16* h    = (bf16*)(ws + o_h);
  bf16* qkvC = (bf16*)(ws + o_qkvC);
  bf16* q    = (bf16*)(ws + o_q);
  bf16* k    = (bf16*)(ws + o_k);
  bf16* vt   = (bf16*)(ws + o_vt);
  bf16* attn = (bf16*)(ws + o_attn);
  float* x2  = (float*)(ws + o_x2);
  bf16* fc1o = (bf16*)(ws + o_fc1o);
  float* out = (float*)d_out;

  cvt_f32_bf16<<<768, 256, 0, stream>>>(qkv_w, qkvw_bf, 786432 / 4);
  cvt_f32_bf16<<<256, 256, 0, stream>>>(proj_w, projw_bf, 262144 / 4);
  cvt_f32_bf16<<<1024, 256, 0, stream>>>(fc1_w, fc1w_bf, 1048576 / 4);
  cvt_f32_bf16<<<1024, 256, 0, stream>>>(fc2_w, fc2w_bf, 1048576 / 4);

  ln_kernel<<<2048, 256, 0, stream>>>(x, ln1_g, ln1_b, h);
  gemm_bt<0><<<dim3(64, 12), 256, 0, stream>>>(h, qkvw_bf, qkv_b, nullptr, qkvC, 8192, 1536, 512);
  reshape_qkv<<<dim3(64, 16), 256, 0, stream>>>(qkvC, q, k, vt);
  attn_kernel<<<dim3(64, 16), 256, 0, stream>>>(q, k, vt, attn);
  gemm_bt<2><<<dim3(64, 4), 256, 0, stream>>>(attn, projw_bf, proj_b, x, x2, 8192, 512, 512);
  ln_kernel<<<2048, 256, 0, stream>>>(x2, ln2_g, ln2_b, h);
  gemm_bt<1><<<dim3(64, 16), 256, 0, stream>>>(h, fc1w_bf, fc1_b, nullptr, fc1o, 8192, 2048, 512);
  gemm_bt<2><<<dim3(64, 4), 256, 0, stream>>>(fc1o, fc2w_bf, fc2_b, x2, out, 8192, 512, 2048);
}

// Round 4
// 295.789 us; speedup vs baseline: 1.4275x; 1.1006x over previous
//
#include <hip/hip_runtime.h>
#include <hip/hip_bf16.h>
#include <string.h>

using bf16 = __hip_bfloat16;
typedef __attribute__((ext_vector_type(8))) short short8;   // 8 x bf16 (4 VGPRs) MFMA A/B frag
typedef __attribute__((ext_vector_type(4))) float f32x4;    // MFMA C/D frag

#define GAS __attribute__((address_space(1)))
#define LAS __attribute__((address_space(3)))

__device__ __forceinline__ void gld_lds16(const void* g, void* l) {
  __builtin_amdgcn_global_load_lds((const GAS void*)g, (LAS void*)l, 16, 0, 0);
}

__device__ __forceinline__ unsigned short f2bfu(float f) {
  bf16 h = __float2bfloat16(f);
  return *reinterpret_cast<unsigned short*>(&h);
}

__device__ __forceinline__ unsigned pack_bf16x2(float lo, float hi) {
  __hip_bfloat162 v = __float22bfloat162_rn(make_float2(lo, hi));
  unsigned u;
  __builtin_memcpy(&u, &v, 4);
  return u;
}

// ---------------- weight f32 -> bf16 ----------------
__global__ __launch_bounds__(256) void cvt_f32_bf16(const float* __restrict__ in,
                                                    bf16* __restrict__ out, int n4) {
  int i = blockIdx.x * 256 + threadIdx.x;
  if (i >= n4) return;
  float4 v = reinterpret_cast<const float4*>(in)[i];
  ushort4 o;
  o.x = f2bfu(v.x); o.y = f2bfu(v.y); o.z = f2bfu(v.z); o.w = f2bfu(v.w);
  reinterpret_cast<ushort4*>(out)[i] = o;
}

// ---------------- LayerNorm (fp32 in, bf16 out), one wave per 512-row ----------------
__global__ __launch_bounds__(256) void ln_kernel(const float* __restrict__ x,
                                                 const float* __restrict__ g,
                                                 const float* __restrict__ b,
                                                 bf16* __restrict__ out) {
  const int row = blockIdx.x * 4 + (threadIdx.x >> 6);
  const int lane = threadIdx.x & 63;
  const float4* xr = reinterpret_cast<const float4*>(x + (size_t)row * 512);
  float4 v0 = xr[lane], v1 = xr[64 + lane];
  float s  = v0.x + v0.y + v0.z + v0.w + v1.x + v1.y + v1.z + v1.w;
  float s2 = v0.x*v0.x + v0.y*v0.y + v0.z*v0.z + v0.w*v0.w
           + v1.x*v1.x + v1.y*v1.y + v1.z*v1.z + v1.w*v1.w;
  #pragma unroll
  for (int d = 1; d < 64; d <<= 1) { s += __shfl_xor(s, d); s2 += __shfl_xor(s2, d); }
  const float mu = s * (1.0f / 512.0f);
  const float var = s2 * (1.0f / 512.0f) - mu * mu;
  const float rstd = rsqrtf(var + 1e-5f);
  const float4* g4 = reinterpret_cast<const float4*>(g);
  const float4* b4 = reinterpret_cast<const float4*>(b);
  float4 ga = g4[lane], gb = g4[64 + lane], ba = b4[lane], bb = b4[64 + lane];
  ushort4 o0, o1;
  o0.x = f2bfu((v0.x - mu) * rstd * ga.x + ba.x);
  o0.y = f2bfu((v0.y - mu) * rstd * ga.y + ba.y);
  o0.z = f2bfu((v0.z - mu) * rstd * ga.z + ba.z);
  o0.w = f2bfu((v0.w - mu) * rstd * ga.w + ba.w);
  o1.x = f2bfu((v1.x - mu) * rstd * gb.x + bb.x);
  o1.y = f2bfu((v1.y - mu) * rstd * gb.y + bb.y);
  o1.z = f2bfu((v1.z - mu) * rstd * gb.z + bb.z);
  o1.w = f2bfu((v1.w - mu) * rstd * gb.w + bb.w);
  ushort4* orow = reinterpret_cast<ushort4*>(out + (size_t)row * 512);
  orow[lane] = o0;
  orow[64 + lane] = o1;
}

// ---------------- GEMM: C[M,N] = A[M,K] * B[N,K]^T (+bias, epilogue) ----------------
template <int EPI>
__global__ __launch_bounds__(256) void gemm_bt(const bf16* __restrict__ A,
                                               const bf16* __restrict__ B,
                                               const float* __restrict__ bias,
                                               const float* __restrict__ resid,
                                               void* __restrict__ Cv,
                                               int M, int N, int K) {
  __shared__ bf16 As[128 * 32];
  __shared__ bf16 Bs[128 * 32];
  const int tid = threadIdx.x;
  const int lane = tid & 63, wid = tid >> 6;
  const int lr = lane & 15, lg = lane >> 4;
  const int row0 = blockIdx.x * 128, col0 = blockIdx.y * 128;
  const int wr = (wid >> 1) * 64, wc = (wid & 1) * 64;
  f32x4 acc[4][4] = {};
  const int r1 = tid >> 2,          c1 = (tid & 3) * 8;
  const int r2 = (256 + tid) >> 2,  c2 = ((256 + tid) & 3) * 8;
  for (int kt = 0; kt < K; kt += 32) {
    __syncthreads();
    gld_lds16(A + (size_t)(row0 + r1) * K + kt + c1, As + tid * 8);
    gld_lds16(A + (size_t)(row0 + r2) * K + kt + c2, As + (256 + tid) * 8);
    gld_lds16(B + (size_t)(col0 + r1) * K + kt + c1, Bs + tid * 8);
    gld_lds16(B + (size_t)(col0 + r2) * K + kt + c2, Bs + (256 + tid) * 8);
    __syncthreads();
    short8 af[4], bfr[4];
    #pragma unroll
    for (int mi = 0; mi < 4; ++mi)
      af[mi] = *reinterpret_cast<const short8*>(&As[(wr + mi * 16 + lr) * 32 + lg * 8]);
    #pragma unroll
    for (int nj = 0; nj < 4; ++nj)
      bfr[nj] = *reinterpret_cast<const short8*>(&Bs[(wc + nj * 16 + lr) * 32 + lg * 8]);
    #pragma unroll
    for (int mi = 0; mi < 4; ++mi)
      #pragma unroll
      for (int nj = 0; nj < 4; ++nj)
        acc[mi][nj] = __builtin_amdgcn_mfma_f32_16x16x32_bf16(af[mi], bfr[nj], acc[mi][nj], 0, 0, 0);
  }
  #pragma unroll
  for (int mi = 0; mi < 4; ++mi) {
    #pragma unroll
    for (int nj = 0; nj < 4; ++nj) {
      const int col = col0 + wc + nj * 16 + lr;
      const float bv = bias ? bias[col] : 0.0f;
      #pragma unroll
      for (int rg = 0; rg < 4; ++rg) {
        const int row = row0 + wr + mi * 16 + lg * 4 + rg;
        float v = acc[mi][nj][rg] + bv;
        if constexpr (EPI == 1) v = 0.5f * v * (1.0f + erff(v * 0.70710678118654752f));
        if constexpr (EPI == 2) {
          reinterpret_cast<float*>(Cv)[(size_t)row * N + col] = v + resid[(size_t)row * N + col];
        } else {
          reinterpret_cast<bf16*>(Cv)[(size_t)row * N + col] = __float2bfloat16(v);
        }
      }
    }
  }
}

// ---------------- reshape QKV (q pre-scaled by 0.125*log2e for exp2-domain softmax) ----------------
__global__ __launch_bounds__(256) void reshape_qkv(const bf16* __restrict__ C,
                                                   bf16* __restrict__ q,
                                                   bf16* __restrict__ k,
                                                   bf16* __restrict__ vt) {
  const int nt = blockIdx.x;
  const int bh = blockIdx.y;
  const int b = bh >> 3, h = bh & 7;
  __shared__ bf16 vs[64][65];
  const int tid = threadIdx.x;
  const float qs = 0.125f * 1.44269504088896340736f;
  #pragma unroll
  for (int i = 0; i < 16; ++i) {
    const int idx = i * 256 + tid;
    const int rr = idx >> 6, c = idx & 63;
    const size_t crow = ((size_t)b * 4096 + nt * 64 + rr) * 1536;
    const size_t onb = ((size_t)bh * 4096 + nt * 64 + rr) * 64 + c;
    q[onb] = __float2bfloat16(__bfloat162float(C[crow + h * 64 + c]) * qs);
    k[onb] = C[crow + 512 + h * 64 + c];
    vs[rr][c] = C[crow + 1024 + h * 64 + c];
  }
  __syncthreads();
  #pragma unroll
  for (int i = 0; i < 16; ++i) {
    const int idx = i * 256 + tid;
    const int d = idx >> 6, n = idx & 63;
    vt[((size_t)bh * 64 + d) * 4096 + nt * 64 + n] = vs[n][d];
  }
}

// ---------------- flash attention: QBLK=64, hoisted swizzled addresses, x2-unrolled dbuf ----------------
__global__ __launch_bounds__(256, 4) void attn_kernel(const bf16* __restrict__ Q,
                                                      const bf16* __restrict__ K,
                                                      const bf16* __restrict__ Vt,
                                                      bf16* __restrict__ Out) {
  const int qt = blockIdx.x;   // 0..63
  const int bh = blockIdx.y;   // 0..15
  const int b = bh >> 3, h = bh & 7;
  __shared__ bf16 QP[4096];       // 8KB: Q tile [64][64] swz; per-wave P region after Q->regs
  __shared__ bf16 Ks[2][4096];    // 2 x 8KB [64 kv][64 d] swz
  __shared__ bf16 Vs[2][4096];    // 2 x 8KB [64 d][64 kv] swz
  const int tid = threadIdx.x, wid = tid >> 6, lane = tid & 63;
  const int lr = lane & 15, lg = lane >> 4;
  const int xsw = (lr & 7) << 4;
  // loop-invariant fragment-read lane bases (within a [64 rows][128B] swz tile)
  const int fb0 = lr * 128 + ((lg * 16) ^ xsw);
  const int fb1 = lr * 128 + ((64 + lg * 16) ^ xsw);
  const char* Qg = (const char*)(Q + ((size_t)bh * 4096 + qt * 64) * 64);
  const char* Kg = (const char*)(K + (size_t)bh * 4096 * 64);
  const char* Vg = (const char*)(Vt + (size_t)bh * 64 * 4096);
  // staging per-lane constants
  const int ph0 = tid * 16, ph1 = (256 + tid) * 16;
  const int sr0 = ph0 >> 7, sr1 = ph1 >> 7;
  const int lb0 = ph0 ^ ((sr0 & 7) << 4), lb1 = ph1 ^ ((sr1 & 7) << 4);
  int vK0 = lb0, vK1 = lb1;                                   // K src voffset (+=8192/tile)
  int vV0 = sr0 * 8192 + (lb0 & 127), vV1 = sr1 * 8192 + (lb1 & 127);  // V src (+=128/tile)

  // ---- stage Q (pre-swizzled source, linear LDS dest) ----
  gld_lds16(Qg + lb0, (char*)QP + ph0);
  gld_lds16(Qg + lb1, (char*)QP + ph1);
  // ---- stage KV tile 0 -> buf 0 ----
  gld_lds16(Kg + vK0, (char*)Ks[0] + ph0);
  gld_lds16(Kg + vK1, (char*)Ks[0] + ph1);
  gld_lds16(Vg + vV0, (char*)Vs[0] + ph0);
  gld_lds16(Vg + vV1, (char*)Vs[0] + ph1);
  vK0 += 8192; vK1 += 8192; vV0 += 128; vV1 += 128;
  __syncthreads();
  // ---- Q frags -> registers; P-region pointers (reuse this wave's own Q rows) ----
  const char* bpA0 = (const char*)QP + wid * 2048 + fb0;
  const char* bpA1 = (const char*)QP + wid * 2048 + fb1;
  const short8 bq0 = *reinterpret_cast<const short8*>(bpA0);
  const short8 bq1 = *reinterpret_cast<const short8*>(bpA1);
  char* pwp[4];
  #pragma unroll
  for (int nk = 0; nk < 4; ++nk)
    pwp[nk] = (char*)QP + wid * 2048 + lr * 128 + ((nk * 32 + lg * 8) ^ xsw);

  f32x4 Oa[4] = {};
  float mrow = -1e30f, lrow = 0.0f;

#define ATTN_STAGE(BUF) do {                                   \
    gld_lds16(Kg + vK0, (char*)Ks[BUF] + ph0);                 \
    gld_lds16(Kg + vK1, (char*)Ks[BUF] + ph1);                 \
    gld_lds16(Vg + vV0, (char*)Vs[BUF] + ph0);                 \
    gld_lds16(Vg + vV1, (char*)Vs[BUF] + ph1);                 \
    vK0 += 8192; vK1 += 8192; vV0 += 128; vV1 += 128;          \
  } while (0)

#define ATTN_COMPUTE(BUF) do {                                                       \
    const char* ksb = (const char*)Ks[BUF];                                          \
    const char* vsb = (const char*)Vs[BUF];                                          \
    short8 ak0[4], ak1[4];                                                           \
    _Pragma("unroll")                                                                \
    for (int nk = 0; nk < 4; ++nk) {                                                 \
      ak0[nk] = *reinterpret_cast<const short8*>(ksb + nk * 2048 + fb0);             \
      ak1[nk] = *reinterpret_cast<const short8*>(ksb + nk * 2048 + fb1);             \
    }                                                                                \
    f32x4 Sa[4];                                                                     \
    __builtin_amdgcn_s_setprio(1);                                                   \
    _Pragma("unroll")                                                                \
    for (int nk = 0; nk < 4; ++nk) {                                                 \
      f32x4 z = {0.0f, 0.0f, 0.0f, 0.0f};                                            \
      z = __builtin_amdgcn_mfma_f32_16x16x32_bf16(ak0[nk], bq0, z, 0, 0, 0);         \
      Sa[nk] = __builtin_amdgcn_mfma_f32_16x16x32_bf16(ak1[nk], bq1, z, 0, 0, 0);    \
    }                                                                                \
    __builtin_amdgcn_s_setprio(0);                                                   \
    float t0 = fmaxf(fmaxf(Sa[0][0], Sa[0][1]), fmaxf(Sa[0][2], Sa[0][3]));          \
    float t1 = fmaxf(fmaxf(Sa[1][0], Sa[1][1]), fmaxf(Sa[1][2], Sa[1][3]));          \
    float t2 = fmaxf(fmaxf(Sa[2][0], Sa[2][1]), fmaxf(Sa[2][2], Sa[2][3]));          \
    float t3 = fmaxf(fmaxf(Sa[3][0], Sa[3][1]), fmaxf(Sa[3][2], Sa[3][3]));          \
    float rmax = fmaxf(fmaxf(t0, t1), fmaxf(t2, t3));                                \
    rmax = fmaxf(rmax, __shfl_xor(rmax, 16));                                        \
    rmax = fmaxf(rmax, __shfl_xor(rmax, 32));                                        \
    if (!__all(rmax <= mrow + 8.0f)) {                                               \
      const float mnew = fmaxf(mrow, rmax);                                          \
      const float fsc = __builtin_amdgcn_exp2f(mrow - mnew);                         \
      lrow *= fsc;                                                                   \
      _Pragma("unroll")                                                              \
      for (int db = 0; db < 4; ++db) {                                               \
        Oa[db][0] *= fsc; Oa[db][1] *= fsc; Oa[db][2] *= fsc; Oa[db][3] *= fsc;      \
      }                                                                              \
      mrow = mnew;                                                                   \
    }                                                                                \
    _Pragma("unroll")                                                                \
    for (int nk = 0; nk < 4; ++nk) {                                                 \
      Sa[nk][0] = __builtin_amdgcn_exp2f(Sa[nk][0] - mrow);                          \
      Sa[nk][1] = __builtin_amdgcn_exp2f(Sa[nk][1] - mrow);                          \
      Sa[nk][2] = __builtin_amdgcn_exp2f(Sa[nk][2] - mrow);                          \
      Sa[nk][3] = __builtin_amdgcn_exp2f(Sa[nk][3] - mrow);                          \
    }                                                                                \
    float s0 = (Sa[0][0] + Sa[0][1]) + (Sa[0][2] + Sa[0][3]);                        \
    float s1 = (Sa[1][0] + Sa[1][1]) + (Sa[1][2] + Sa[1][3]);                        \
    float s2 = (Sa[2][0] + Sa[2][1]) + (Sa[2][2] + Sa[2][3]);                        \
    float s3 = (Sa[3][0] + Sa[3][1]) + (Sa[3][2] + Sa[3][3]);                        \
    float rsum = (s0 + s1) + (s2 + s3);                                              \
    rsum += __shfl_xor(rsum, 16);                                                    \
    rsum += __shfl_xor(rsum, 32);                                                    \
    lrow += rsum;                                                                    \
    _Pragma("unroll")                                                                \
    for (int nk = 0; nk < 4; ++nk) {                                                 \
      *reinterpret_cast<unsigned*>(pwp[nk])     = pack_bf16x2(Sa[nk][0], Sa[nk][1]); \
      *reinterpret_cast<unsigned*>(pwp[nk] + 4) = pack_bf16x2(Sa[nk][2], Sa[nk][3]); \
    }                                                                                \
    short8 av0[4], av1[4];                                                           \
    _Pragma("unroll")                                                                \
    for (int db = 0; db < 4; ++db) {                                                 \
      av0[db] = *reinterpret_cast<const short8*>(vsb + db * 2048 + fb0);             \
      av1[db] = *reinterpret_cast<const short8*>(vsb + db * 2048 + fb1);             \
    }                                                                                \
    const short8 bp0 = *reinterpret_cast<const short8*>(bpA0);                       \
    const short8 bp1 = *reinterpret_cast<const short8*>(bpA1);                       \
    __builtin_amdgcn_s_setprio(1);                                                   \
    _Pragma("unroll")                                                                \
    for (int db = 0; db < 4; ++db) {                                                 \
      Oa[db] = __builtin_amdgcn_mfma_f32_16x16x32_bf16(av0[db], bp0, Oa[db], 0, 0, 0); \
      Oa[db] = __builtin_amdgcn_mfma_f32_16x16x32_bf16(av1[db], bp1, Oa[db], 0, 0, 0); \
    }                                                                                \
    __builtin_amdgcn_s_setprio(0);                                                   \
  } while (0)

  // main loop: tiles 0..61 (x2 unrolled), tail tiles 62,63
  for (int tt = 0; tt < 31; ++tt) {
    __syncthreads();
    ATTN_STAGE(1);
    ATTN_COMPUTE(0);
    __syncthreads();
    ATTN_STAGE(0);
    ATTN_COMPUTE(1);
  }
  __syncthreads();
  ATTN_STAGE(1);
  ATTN_COMPUTE(0);
  __syncthreads();
  ATTN_COMPUTE(1);

#undef ATTN_STAGE
#undef ATTN_COMPUTE

  // ---- normalize + store: lane q=lr, d = db*16 + lg*4 + e ----
  const float linv = 1.0f / lrow;
  const int n = qt * 64 + wid * 16 + lr;
  #pragma unroll
  for (int db = 0; db < 4; ++db) {
    uint2 st;
    st.x = pack_bf16x2(Oa[db][0] * linv, Oa[db][1] * linv);
    st.y = pack_bf16x2(Oa[db][2] * linv, Oa[db][3] * linv);
    *reinterpret_cast<uint2*>(Out + ((size_t)b * 4096 + n) * 512 + h * 64 + db * 16 + lg * 4) = st;
  }
}

// ---------------- host ----------------
extern "C" void kernel_launch(void* const* d_in, const int* in_sizes, int n_in,
                              void* d_out, int out_size, void* d_ws, size_t ws_size,
                              hipStream_t stream) {
  const float* x      = (const float*)d_in[0];
  const float* ln1_g  = (const float*)d_in[1];
  const float* ln1_b  = (const float*)d_in[2];
  const float* ln2_g  = (const float*)d_in[3];
  const float* ln2_b  = (const float*)d_in[4];
  const float* qkv_w  = (const float*)d_in[5];
  const float* qkv_b  = (const float*)d_in[6];
  const float* proj_w = (const float*)d_in[7];
  const float* proj_b = (const float*)d_in[8];
  const float* fc1_w  = (const float*)d_in[9];
  const float* fc1_b  = (const float*)d_in[10];
  const float* fc2_w  = (const float*)d_in[11];
  const float* fc2_b  = (const float*)d_in[12];

  char* ws = (char*)d_ws;
  constexpr size_t o_qkvw = 0;
  constexpr size_t o_projw = 1572864;
  constexpr size_t o_fc1w  = 2097152;
  constexpr size_t o_fc2w  = 4194304;
  constexpr size_t o_h     = 6291456;
  constexpr size_t o_qkvC  = 14680064;
  constexpr size_t o_q     = 39845888;
  constexpr size_t o_k     = 48234496;
  constexpr size_t o_vt    = 56623104;
  constexpr size_t o_attn  = 65011712;
  constexpr size_t o_x2    = 73400320;
  constexpr size_t o_fc1o  = o_qkvC;
  constexpr size_t needed  = 90177536;
  if (ws_size < needed) return;

  bf16* qkvw_bf = (bf16*)(ws + o_qkvw);
  bf16* projw_bf = (bf16*)(ws + o_projw);
  bf16* fc1w_bf = (bf16*)(ws + o_fc1w);
  bf16* fc2w_bf = (bf16*)(ws + o_fc2w);
  bf16* h    = (bf16*)(ws + o_h);
  bf16* qkvC = (bf16*)(ws + o_qkvC);
  bf16* q    = (bf16*)(ws + o_q);
  bf16* k    = (bf16*)(ws + o_k);
  bf16* vt   = (bf16*)(ws + o_vt);
  bf16* attn = (bf16*)(ws + o_attn);
  float* x2  = (float*)(ws + o_x2);
  bf16* fc1o = (bf16*)(ws + o_fc1o);
  float* out = (float*)d_out;

  cvt_f32_bf16<<<768, 256, 0, stream>>>(qkv_w, qkvw_bf, 786432 / 4);
  cvt_f32_bf16<<<256, 256, 0, stream>>>(proj_w, projw_bf, 262144 / 4);
  cvt_f32_bf16<<<1024, 256, 0, stream>>>(fc1_w, fc1w_bf, 1048576 / 4);
  cvt_f32_bf16<<<1024, 256, 0, stream>>>(fc2_w, fc2w_bf, 1048576 / 4);

  ln_kernel<<<2048, 256, 0, stream>>>(x, ln1_g, ln1_b, h);
  gemm_bt<0><<<dim3(64, 12), 256, 0, stream>>>(h, qkvw_bf, qkv_b, nullptr, qkvC, 8192, 1536, 512);
  reshape_qkv<<<dim3(64, 16), 256, 0, stream>>>(qkvC, q, k, vt);
  attn_kernel<<<dim3(64, 16), 256, 0, stream>>>(q, k, vt, attn);
  gemm_bt<2><<<dim3(64, 4), 256, 0, stream>>>(attn, projw_bf, proj_b, x, x2, 8192, 512, 512);
  ln_kernel<<<2048, 256, 0, stream>>>(x2, ln2_g, ln2_b, h);
  gemm_bt<1><<<dim3(64, 16), 256, 0, stream>>>(h, fc1w_bf, fc1_b, nullptr, fc1o, 8192, 2048, 512);
  gemm_bt<2><<<dim3(64, 4), 256, 0, stream>>>(fc1o, fc2w_bf, fc2_b, x2, out, 8192, 512, 2048);
}

// Round 5
// 265.936 us; speedup vs baseline: 1.5878x; 1.1123x over previous
//
#include <hip/hip_runtime.h>
#include <hip/hip_bf16.h>
#include <string.h>

using bf16 = __hip_bfloat16;
typedef __attribute__((ext_vector_type(8))) short short8;   // 8 x bf16 (4 VGPRs) MFMA A/B frag
typedef __attribute__((ext_vector_type(4))) float f32x4;    // MFMA C/D frag

#define GAS __attribute__((address_space(1)))
#define LAS __attribute__((address_space(3)))

__device__ __forceinline__ void gld_lds16(const void* g, void* l) {
  __builtin_amdgcn_global_load_lds((const GAS void*)g, (LAS void*)l, 16, 0, 0);
}

__device__ __forceinline__ unsigned short f2bfu(float f) {
  bf16 h = __float2bfloat16(f);
  return *reinterpret_cast<unsigned short*>(&h);
}

__device__ __forceinline__ unsigned pack_bf16x2(float lo, float hi) {
  __hip_bfloat162 v = __float22bfloat162_rn(make_float2(lo, hi));
  unsigned u;
  __builtin_memcpy(&u, &v, 4);
  return u;
}

// ---------------- all weights f32 -> bf16 in one launch ----------------
__global__ __launch_bounds__(256) void cvt_all(const float* __restrict__ w0, bf16* __restrict__ o0,
                                               const float* __restrict__ w1, bf16* __restrict__ o1,
                                               const float* __restrict__ w2, bf16* __restrict__ o2,
                                               const float* __restrict__ w3, bf16* __restrict__ o3) {
  int i = blockIdx.x * 256 + threadIdx.x;   // f4 index, total 786432
  const float* src; bf16* dst; int off;
  if (i < 196608)      { src = w0; dst = o0; off = i; }
  else if (i < 262144) { src = w1; dst = o1; off = i - 196608; }
  else if (i < 524288) { src = w2; dst = o2; off = i - 262144; }
  else                 { src = w3; dst = o3; off = i - 524288; }
  float4 v = reinterpret_cast<const float4*>(src)[off];
  ushort4 o;
  o.x = f2bfu(v.x); o.y = f2bfu(v.y); o.z = f2bfu(v.z); o.w = f2bfu(v.w);
  reinterpret_cast<ushort4*>(dst)[off] = o;
}

// ---------------- LayerNorm (fp32 in, bf16 out), one wave per 512-row ----------------
__global__ __launch_bounds__(256) void ln_kernel(const float* __restrict__ x,
                                                 const float* __restrict__ g,
                                                 const float* __restrict__ b,
                                                 bf16* __restrict__ out) {
  const int row = blockIdx.x * 4 + (threadIdx.x >> 6);
  const int lane = threadIdx.x & 63;
  const float4* xr = reinterpret_cast<const float4*>(x + (size_t)row * 512);
  float4 v0 = xr[lane], v1 = xr[64 + lane];
  float s  = v0.x + v0.y + v0.z + v0.w + v1.x + v1.y + v1.z + v1.w;
  float s2 = v0.x*v0.x + v0.y*v0.y + v0.z*v0.z + v0.w*v0.w
           + v1.x*v1.x + v1.y*v1.y + v1.z*v1.z + v1.w*v1.w;
  #pragma unroll
  for (int d = 1; d < 64; d <<= 1) { s += __shfl_xor(s, d); s2 += __shfl_xor(s2, d); }
  const float mu = s * (1.0f / 512.0f);
  const float var = s2 * (1.0f / 512.0f) - mu * mu;
  const float rstd = rsqrtf(var + 1e-5f);
  const float4* g4 = reinterpret_cast<const float4*>(g);
  const float4* b4 = reinterpret_cast<const float4*>(b);
  float4 ga = g4[lane], gb = g4[64 + lane], ba = b4[lane], bb = b4[64 + lane];
  ushort4 o0, o1;
  o0.x = f2bfu((v0.x - mu) * rstd * ga.x + ba.x);
  o0.y = f2bfu((v0.y - mu) * rstd * ga.y + ba.y);
  o0.z = f2bfu((v0.z - mu) * rstd * ga.z + ba.z);
  o0.w = f2bfu((v0.w - mu) * rstd * ga.w + ba.w);
  o1.x = f2bfu((v1.x - mu) * rstd * gb.x + bb.x);
  o1.y = f2bfu((v1.y - mu) * rstd * gb.y + bb.y);
  o1.z = f2bfu((v1.z - mu) * rstd * gb.z + bb.z);
  o1.w = f2bfu((v1.w - mu) * rstd * gb.w + bb.w);
  ushort4* orow = reinterpret_cast<ushort4*>(out + (size_t)row * 512);
  orow[lane] = o0;
  orow[64 + lane] = o1;
}

// ---------------- GEMM 128x128: C[M,N] = A[M,K] * B[N,K]^T (+bias, epilogue) ----------------
template <int EPI>
__global__ __launch_bounds__(256) void gemm_bt(const bf16* __restrict__ A,
                                               const bf16* __restrict__ B,
                                               const float* __restrict__ bias,
                                               const float* __restrict__ resid,
                                               void* __restrict__ Cv,
                                               int M, int N, int K) {
  __shared__ bf16 As[128 * 32];
  __shared__ bf16 Bs[128 * 32];
  const int tid = threadIdx.x;
  const int lane = tid & 63, wid = tid >> 6;
  const int lr = lane & 15, lg = lane >> 4;
  const int row0 = blockIdx.x * 128, col0 = blockIdx.y * 128;
  const int wr = (wid >> 1) * 64, wc = (wid & 1) * 64;
  f32x4 acc[4][4] = {};
  const int r1 = tid >> 2,          c1 = (tid & 3) * 8;
  const int r2 = (256 + tid) >> 2,  c2 = ((256 + tid) & 3) * 8;
  for (int kt = 0; kt < K; kt += 32) {
    __syncthreads();
    gld_lds16(A + (size_t)(row0 + r1) * K + kt + c1, As + tid * 8);
    gld_lds16(A + (size_t)(row0 + r2) * K + kt + c2, As + (256 + tid) * 8);
    gld_lds16(B + (size_t)(col0 + r1) * K + kt + c1, Bs + tid * 8);
    gld_lds16(B + (size_t)(col0 + r2) * K + kt + c2, Bs + (256 + tid) * 8);
    __syncthreads();
    short8 af[4], bfr[4];
    #pragma unroll
    for (int mi = 0; mi < 4; ++mi)
      af[mi] = *reinterpret_cast<const short8*>(&As[(wr + mi * 16 + lr) * 32 + lg * 8]);
    #pragma unroll
    for (int nj = 0; nj < 4; ++nj)
      bfr[nj] = *reinterpret_cast<const short8*>(&Bs[(wc + nj * 16 + lr) * 32 + lg * 8]);
    #pragma unroll
    for (int mi = 0; mi < 4; ++mi)
      #pragma unroll
      for (int nj = 0; nj < 4; ++nj)
        acc[mi][nj] = __builtin_amdgcn_mfma_f32_16x16x32_bf16(af[mi], bfr[nj], acc[mi][nj], 0, 0, 0);
  }
  #pragma unroll
  for (int mi = 0; mi < 4; ++mi) {
    #pragma unroll
    for (int nj = 0; nj < 4; ++nj) {
      const int col = col0 + wc + nj * 16 + lr;
      const float bv = bias ? bias[col] : 0.0f;
      #pragma unroll
      for (int rg = 0; rg < 4; ++rg) {
        const int row = row0 + wr + mi * 16 + lg * 4 + rg;
        float v = acc[mi][nj][rg] + bv;
        if constexpr (EPI == 1) v = 0.5f * v * (1.0f + erff(v * 0.70710678118654752f));
        if constexpr (EPI == 2) {
          reinterpret_cast<float*>(Cv)[(size_t)row * N + col] = v + resid[(size_t)row * N + col];
        } else {
          reinterpret_cast<bf16*>(Cv)[(size_t)row * N + col] = __float2bfloat16(v);
        }
      }
    }
  }
}

// ---------------- GEMM 64x64 (BK=64, swizzled LDS): for N=512 GEMMs, 1024-block grids ----------------
template <int EPI>
__global__ __launch_bounds__(256) void gemm_bt64(const bf16* __restrict__ A,
                                                 const bf16* __restrict__ B,
                                                 const float* __restrict__ bias,
                                                 const float* __restrict__ resid,
                                                 void* __restrict__ Cv,
                                                 int M, int N, int K) {
  __shared__ bf16 As[64 * 64];   // [64 rows][128B], XOR-swizzled
  __shared__ bf16 Bs[64 * 64];
  const int tid = threadIdx.x;
  const int lane = tid & 63, wid = tid >> 6;
  const int lr = lane & 15, lg = lane >> 4;
  const int row0 = blockIdx.x * 64, col0 = blockIdx.y * 64;
  const int wr = (wid >> 1) * 32, wc = (wid & 1) * 32;
  f32x4 acc[2][2] = {};
  const int xsw = (lr & 7) << 4;
  const int fb0 = lr * 128 + ((lg * 16) ^ xsw);
  const int fb1 = lr * 128 + ((64 + lg * 16) ^ xsw);
  const int ph0 = tid * 16, ph1 = (256 + tid) * 16;
  const int r0 = ph0 >> 7, r1 = ph1 >> 7;
  const int lb0 = ph0 ^ ((r0 & 7) << 4), lb1 = ph1 ^ ((r1 & 7) << 4);
  const char* Ab0 = (const char*)A + (size_t)(row0 + r0) * K * 2 + (lb0 & 127);
  const char* Ab1 = (const char*)A + (size_t)(row0 + r1) * K * 2 + (lb1 & 127);
  const char* Bb0 = (const char*)B + (size_t)(col0 + r0) * K * 2 + (lb0 & 127);
  const char* Bb1 = (const char*)B + (size_t)(col0 + r1) * K * 2 + (lb1 & 127);
  for (int kt = 0; kt < K; kt += 64) {
    __syncthreads();
    gld_lds16(Ab0 + kt * 2, (char*)As + ph0);
    gld_lds16(Ab1 + kt * 2, (char*)As + ph1);
    gld_lds16(Bb0 + kt * 2, (char*)Bs + ph0);
    gld_lds16(Bb1 + kt * 2, (char*)Bs + ph1);
    __syncthreads();
    short8 af0[2], af1[2], bf0[2], bf1[2];
    #pragma unroll
    for (int mi = 0; mi < 2; ++mi) {
      af0[mi] = *reinterpret_cast<const short8*>((const char*)As + (wr + mi * 16) * 128 + fb0);
      af1[mi] = *reinterpret_cast<const short8*>((const char*)As + (wr + mi * 16) * 128 + fb1);
    }
    #pragma unroll
    for (int nj = 0; nj < 2; ++nj) {
      bf0[nj] = *reinterpret_cast<const short8*>((const char*)Bs + (wc + nj * 16) * 128 + fb0);
      bf1[nj] = *reinterpret_cast<const short8*>((const char*)Bs + (wc + nj * 16) * 128 + fb1);
    }
    #pragma unroll
    for (int mi = 0; mi < 2; ++mi)
      #pragma unroll
      for (int nj = 0; nj < 2; ++nj) {
        acc[mi][nj] = __builtin_amdgcn_mfma_f32_16x16x32_bf16(af0[mi], bf0[nj], acc[mi][nj], 0, 0, 0);
        acc[mi][nj] = __builtin_amdgcn_mfma_f32_16x16x32_bf16(af1[mi], bf1[nj], acc[mi][nj], 0, 0, 0);
      }
  }
  #pragma unroll
  for (int mi = 0; mi < 2; ++mi) {
    #pragma unroll
    for (int nj = 0; nj < 2; ++nj) {
      const int col = col0 + wc + nj * 16 + lr;
      const float bv = bias ? bias[col] : 0.0f;
      #pragma unroll
      for (int rg = 0; rg < 4; ++rg) {
        const int row = row0 + wr + mi * 16 + lg * 4 + rg;
        float v = acc[mi][nj][rg] + bv;
        if constexpr (EPI == 1) v = 0.5f * v * (1.0f + erff(v * 0.70710678118654752f));
        if constexpr (EPI == 2) {
          reinterpret_cast<float*>(Cv)[(size_t)row * N + col] = v + resid[(size_t)row * N + col];
        } else {
          reinterpret_cast<bf16*>(Cv)[(size_t)row * N + col] = __float2bfloat16(v);
        }
      }
    }
  }
}

// ---------------- reshape QKV: q,k [BH,N,D] (q pre-scaled 0.125*log2e); V -> frag-tiled VF ----------------
// VF layout: [bh][t(64)][db(4)][kk(2)][lane(64)][8 bf16]; frag value = V[n = t*64 + kk*32 + lg*8 + j][d = db*16 + lr]
__global__ __launch_bounds__(256) void reshape_qkv(const bf16* __restrict__ C,
                                                   bf16* __restrict__ q,
                                                   bf16* __restrict__ k,
                                                   bf16* __restrict__ vf) {
  const int nt = blockIdx.x;   // 64-row tile == attn kv-tile index
  const int bh = blockIdx.y;
  const int b = bh >> 3, h = bh & 7;
  __shared__ bf16 vs[64][65];  // [d][n] transposed tile
  const int tid = threadIdx.x;
  const float qs = 0.125f * 1.44269504088896340736f;
  #pragma unroll
  for (int i = 0; i < 16; ++i) {
    const int idx = i * 256 + tid;
    const int rr = idx >> 6, c = idx & 63;
    const size_t crow = ((size_t)b * 4096 + nt * 64 + rr) * 1536;
    const size_t onb = ((size_t)bh * 4096 + nt * 64 + rr) * 64 + c;
    q[onb] = __float2bfloat16(__bfloat162float(C[crow + h * 64 + c]) * qs);
    k[onb] = C[crow + 512 + h * 64 + c];
    vs[c][rr] = C[crow + 1024 + h * 64 + c];   // store transposed: vs[d][n]
  }
  __syncthreads();
  #pragma unroll
  for (int i = 0; i < 2; ++i) {
    const int slot = i * 256 + tid;            // 0..511
    const int db = slot >> 7, kk = (slot >> 6) & 1, l = slot & 63;
    const int lr = l & 15, lg = l >> 4;
    const short8 wv = *reinterpret_cast<const short8*>(&vs[db * 16 + lr][kk * 32 + lg * 8]);
    bf16* dst = vf + ((size_t)bh * 64 + nt) * 4096 + (size_t)(db * 2 + kk) * 512 + l * 8;
    *reinterpret_cast<short8*>(dst) = wv;
  }
}

// ---------------- flash attention: QBLK=64, K in swizzled LDS (dbuf), V frag-direct from global ----------------
__global__ __launch_bounds__(256, 4) void attn_kernel(const bf16* __restrict__ Q,
                                                      const bf16* __restrict__ K,
                                                      const bf16* __restrict__ Vf,
                                                      bf16* __restrict__ Out) {
  const int qt = blockIdx.x;   // 0..63
  const int bh = blockIdx.y;   // 0..15
  const int b = bh >> 3, h = bh & 7;
  __shared__ bf16 QP[4096];       // 8KB: Q tile [64][64] swz; per-wave P region after Q->regs
  __shared__ bf16 Ks[2][4096];    // 2 x 8KB [64 kv][64 d] swz
  const int tid = threadIdx.x, wid = tid >> 6, lane = tid & 63;
  const int lr = lane & 15, lg = lane >> 4;
  const int xsw = (lr & 7) << 4;
  const int fb0 = lr * 128 + ((lg * 16) ^ xsw);
  const int fb1 = lr * 128 + ((64 + lg * 16) ^ xsw);
  const char* Qg = (const char*)(Q + ((size_t)bh * 4096 + qt * 64) * 64);
  const char* Kg = (const char*)(K + (size_t)bh * 4096 * 64);
  const char* vlb = (const char*)Vf + (size_t)bh * 524288 + lane * 16;  // V frag base
  // staging per-lane constants
  const int ph0 = tid * 16, ph1 = (256 + tid) * 16;
  const int sr0 = ph0 >> 7, sr1 = ph1 >> 7;
  const int lb0 = ph0 ^ ((sr0 & 7) << 4), lb1 = ph1 ^ ((sr1 & 7) << 4);
  int vK0 = lb0, vK1 = lb1;                     // K src voffset (+=8192/tile)

  // ---- stage Q + K tile 0 ----
  gld_lds16(Qg + lb0, (char*)QP + ph0);
  gld_lds16(Qg + lb1, (char*)QP + ph1);
  gld_lds16(Kg + vK0, (char*)Ks[0] + ph0);
  gld_lds16(Kg + vK1, (char*)Ks[0] + ph1);
  vK0 += 8192; vK1 += 8192;
  __syncthreads();
  // ---- Q frags -> registers; P-region pointers (reuse this wave's own Q rows) ----
  const char* bpA0 = (const char*)QP + wid * 2048 + fb0;
  const char* bpA1 = (const char*)QP + wid * 2048 + fb1;
  const short8 bq0 = *reinterpret_cast<const short8*>(bpA0);
  const short8 bq1 = *reinterpret_cast<const short8*>(bpA1);
  char* pwp[4];
  #pragma unroll
  for (int nk = 0; nk < 4; ++nk)
    pwp[nk] = (char*)QP + wid * 2048 + lr * 128 + ((nk * 32 + lg * 8) ^ xsw);

  f32x4 Oa[4] = {};
  float mrow = -1e30f, lrow = 0.0f;
  int toff = 0;

#define ATTN_STAGE(BUF) do {                                   \
    gld_lds16(Kg + vK0, (char*)Ks[BUF] + ph0);                 \
    gld_lds16(Kg + vK1, (char*)Ks[BUF] + ph1);                 \
    vK0 += 8192; vK1 += 8192;                                  \
  } while (0)

#define ATTN_COMPUTE(BUF) do {                                                       \
    short8 av0[4], av1[4];                                                           \
    _Pragma("unroll")                                                                \
    for (int db = 0; db < 4; ++db) {                                                 \
      av0[db] = *reinterpret_cast<const short8*>(vlb + toff + db * 2048);            \
      av1[db] = *reinterpret_cast<const short8*>(vlb + toff + db * 2048 + 1024);     \
    }                                                                                \
    toff += 8192;                                                                    \
    const char* ksb = (const char*)Ks[BUF];                                          \
    short8 ak0[4], ak1[4];                                                           \
    _Pragma("unroll")                                                                \
    for (int nk = 0; nk < 4; ++nk) {                                                 \
      ak0[nk] = *reinterpret_cast<const short8*>(ksb + nk * 2048 + fb0);             \
      ak1[nk] = *reinterpret_cast<const short8*>(ksb + nk * 2048 + fb1);             \
    }                                                                                \
    f32x4 Sa[4];                                                                     \
    __builtin_amdgcn_s_setprio(1);                                                   \
    _Pragma("unroll")                                                                \
    for (int nk = 0; nk < 4; ++nk) {                                                 \
      f32x4 z = {0.0f, 0.0f, 0.0f, 0.0f};                                            \
      z = __builtin_amdgcn_mfma_f32_16x16x32_bf16(ak0[nk], bq0, z, 0, 0, 0);         \
      Sa[nk] = __builtin_amdgcn_mfma_f32_16x16x32_bf16(ak1[nk], bq1, z, 0, 0, 0);    \
    }                                                                                \
    __builtin_amdgcn_s_setprio(0);                                                   \
    float t0 = fmaxf(fmaxf(Sa[0][0], Sa[0][1]), fmaxf(Sa[0][2], Sa[0][3]));          \
    float t1 = fmaxf(fmaxf(Sa[1][0], Sa[1][1]), fmaxf(Sa[1][2], Sa[1][3]));          \
    float t2 = fmaxf(fmaxf(Sa[2][0], Sa[2][1]), fmaxf(Sa[2][2], Sa[2][3]));          \
    float t3 = fmaxf(fmaxf(Sa[3][0], Sa[3][1]), fmaxf(Sa[3][2], Sa[3][3]));          \
    float rmax = fmaxf(fmaxf(t0, t1), fmaxf(t2, t3));                                \
    rmax = fmaxf(rmax, __shfl_xor(rmax, 16));                                        \
    rmax = fmaxf(rmax, __shfl_xor(rmax, 32));                                        \
    if (!__all(rmax <= mrow + 8.0f)) {                                               \
      const float mnew = fmaxf(mrow, rmax);                                          \
      const float fsc = __builtin_amdgcn_exp2f(mrow - mnew);                         \
      lrow *= fsc;                                                                   \
      _Pragma("unroll")                                                              \
      for (int db = 0; db < 4; ++db) {                                               \
        Oa[db][0] *= fsc; Oa[db][1] *= fsc; Oa[db][2] *= fsc; Oa[db][3] *= fsc;      \
      }                                                                              \
      mrow = mnew;                                                                   \
    }                                                                                \
    _Pragma("unroll")                                                                \
    for (int nk = 0; nk < 4; ++nk) {                                                 \
      Sa[nk][0] = __builtin_amdgcn_exp2f(Sa[nk][0] - mrow);                          \
      Sa[nk][1] = __builtin_amdgcn_exp2f(Sa[nk][1] - mrow);                          \
      Sa[nk][2] = __builtin_amdgcn_exp2f(Sa[nk][2] - mrow);                          \
      Sa[nk][3] = __builtin_amdgcn_exp2f(Sa[nk][3] - mrow);                          \
    }                                                                                \
    float s0 = (Sa[0][0] + Sa[0][1]) + (Sa[0][2] + Sa[0][3]);                        \
    float s1 = (Sa[1][0] + Sa[1][1]) + (Sa[1][2] + Sa[1][3]);                        \
    float s2 = (Sa[2][0] + Sa[2][1]) + (Sa[2][2] + Sa[2][3]);                        \
    float s3 = (Sa[3][0] + Sa[3][1]) + (Sa[3][2] + Sa[3][3]);                        \
    float rsum = (s0 + s1) + (s2 + s3);                                              \
    rsum += __shfl_xor(rsum, 16);                                                    \
    rsum += __shfl_xor(rsum, 32);                                                    \
    lrow += rsum;                                                                    \
    _Pragma("unroll")                                                                \
    for (int nk = 0; nk < 4; ++nk) {                                                 \
      *reinterpret_cast<unsigned*>(pwp[nk])     = pack_bf16x2(Sa[nk][0], Sa[nk][1]); \
      *reinterpret_cast<unsigned*>(pwp[nk] + 4) = pack_bf16x2(Sa[nk][2], Sa[nk][3]); \
    }                                                                                \
    const short8 bp0 = *reinterpret_cast<const short8*>(bpA0);                       \
    const short8 bp1 = *reinterpret_cast<const short8*>(bpA1);                       \
    __builtin_amdgcn_s_setprio(1);                                                   \
    _Pragma("unroll")                                                                \
    for (int db = 0; db < 4; ++db) {                                                 \
      Oa[db] = __builtin_amdgcn_mfma_f32_16x16x32_bf16(av0[db], bp0, Oa[db], 0, 0, 0); \
      Oa[db] = __builtin_amdgcn_mfma_f32_16x16x32_bf16(av1[db], bp1, Oa[db], 0, 0, 0); \
    }                                                                                \
    __builtin_amdgcn_s_setprio(0);                                                   \
  } while (0)

  for (int tt = 0; tt < 31; ++tt) {
    __syncthreads();
    ATTN_STAGE(1);
    ATTN_COMPUTE(0);
    __syncthreads();
    ATTN_STAGE(0);
    ATTN_COMPUTE(1);
  }
  __syncthreads();
  ATTN_STAGE(1);
  ATTN_COMPUTE(0);
  __syncthreads();
  ATTN_COMPUTE(1);

#undef ATTN_STAGE
#undef ATTN_COMPUTE

  // ---- normalize + store: lane q=lr, d = db*16 + lg*4 + e ----
  const float linv = 1.0f / lrow;
  const int n = qt * 64 + wid * 16 + lr;
  #pragma unroll
  for (int db = 0; db < 4; ++db) {
    uint2 st;
    st.x = pack_bf16x2(Oa[db][0] * linv, Oa[db][1] * linv);
    st.y = pack_bf16x2(Oa[db][2] * linv, Oa[db][3] * linv);
    *reinterpret_cast<uint2*>(Out + ((size_t)b * 4096 + n) * 512 + h * 64 + db * 16 + lg * 4) = st;
  }
}

// ---------------- host ----------------
extern "C" void kernel_launch(void* const* d_in, const int* in_sizes, int n_in,
                              void* d_out, int out_size, void* d_ws, size_t ws_size,
                              hipStream_t stream) {
  const float* x      = (const float*)d_in[0];
  const float* ln1_g  = (const float*)d_in[1];
  const float* ln1_b  = (const float*)d_in[2];
  const float* ln2_g  = (const float*)d_in[3];
  const float* ln2_b  = (const float*)d_in[4];
  const float* qkv_w  = (const float*)d_in[5];
  const float* qkv_b  = (const float*)d_in[6];
  const float* proj_w = (const float*)d_in[7];
  const float* proj_b = (const float*)d_in[8];
  const float* fc1_w  = (const float*)d_in[9];
  const float* fc1_b  = (const float*)d_in[10];
  const float* fc2_w  = (const float*)d_in[11];
  const float* fc2_b  = (const float*)d_in[12];

  char* ws = (char*)d_ws;
  constexpr size_t o_qkvw = 0;
  constexpr size_t o_projw = 1572864;
  constexpr size_t o_fc1w  = 2097152;
  constexpr size_t o_fc2w  = 4194304;
  constexpr size_t o_h     = 6291456;
  constexpr size_t o_qkvC  = 14680064;
  constexpr size_t o_q     = 39845888;
  constexpr size_t o_k     = 48234496;
  constexpr size_t o_vt    = 56623104;
  constexpr size_t o_attn  = 65011712;
  constexpr size_t o_x2    = 73400320;
  constexpr size_t o_fc1o  = o_qkvC;
  constexpr size_t needed  = 90177536;
  if (ws_size < needed) return;

  bf16* qkvw_bf = (bf16*)(ws + o_qkvw);
  bf16* projw_bf = (bf16*)(ws + o_projw);
  bf16* fc1w_bf = (bf16*)(ws + o_fc1w);
  bf16* fc2w_bf = (bf16*)(ws + o_fc2w);
  bf16* h    = (bf16*)(ws + o_h);
  bf16* qkvC = (bf16*)(ws + o_qkvC);
  bf16* q    = (bf16*)(ws + o_q);
  bf16* k    = (bf16*)(ws + o_k);
  bf16* vf   = (bf16*)(ws + o_vt);
  bf16* attn = (bf16*)(ws + o_attn);
  float* x2  = (float*)(ws + o_x2);
  bf16* fc1o = (bf16*)(ws + o_fc1o);
  float* out = (float*)d_out;

  cvt_all<<<3072, 256, 0, stream>>>(qkv_w, qkvw_bf, proj_w, projw_bf, fc1_w, fc1w_bf, fc2_w, fc2w_bf);

  ln_kernel<<<2048, 256, 0, stream>>>(x, ln1_g, ln1_b, h);
  gemm_bt<0><<<dim3(64, 12), 256, 0, stream>>>(h, qkvw_bf, qkv_b, nullptr, qkvC, 8192, 1536, 512);
  reshape_qkv<<<dim3(64, 16), 256, 0, stream>>>(qkvC, q, k, vf);
  attn_kernel<<<dim3(64, 16), 256, 0, stream>>>(q, k, vf, attn);
  gemm_bt64<2><<<dim3(128, 8), 256, 0, stream>>>(attn, projw_bf, proj_b, x, x2, 8192, 512, 512);
  ln_kernel<<<2048, 256, 0, stream>>>(x2, ln2_g, ln2_b, h);
  gemm_bt<1><<<dim3(64, 16), 256, 0, stream>>>(h, fc1w_bf, fc1_b, nullptr, fc1o, 8192, 2048, 512);
  gemm_bt64<2><<<dim3(128, 8), 256, 0, stream>>>(fc1o, fc2w_bf, fc2_b, x2, out, 8192, 512, 2048);
}